// Round 4
// baseline (4956.832 us; speedup 1.0000x reference)
//
#include <hip/hip_runtime.h>

#define NB   64
#define NT   30
#define NBT  1920        // NB*NT
#define EE   128
#define KP   28224       // 4*84*84
#define LTK  89          // 3*NT-1
#define NS   5696        // NB*LTK
#define NLY  6
#define NV   18
#define NZ   21          // split-K slabs for patch gemm
#define NBLK 512         // mega grid (2 blocks/CU, co-resident)

typedef unsigned short ushort_t;
using bf16x8 = __attribute__((ext_vector_type(8))) short;
using us8    = __attribute__((ext_vector_type(8))) unsigned short;
using f32x4  = __attribute__((ext_vector_type(4))) float;

__device__ inline ushort_t f2bf(float f){
  union { float f; unsigned u; } v; v.f = f;
  unsigned r = v.u + 0x7FFFu + ((v.u >> 16) & 1u);   // RNE
  return (ushort_t)(r >> 16);
}
__device__ inline float bf2f(ushort_t h){
  union { unsigned u; float f; } v; v.u = ((unsigned)h) << 16; return v.f;
}

// ---------------- grid barrier (all NBLK blocks co-resident) ---------------
__device__ inline void gbar(unsigned* ctl, unsigned ord){
  __syncthreads();
  if (threadIdx.x == 0){
    __threadfence();
    __hip_atomic_fetch_add(&ctl[(blockIdx.x & 7) * 32], 1u,
                           __ATOMIC_RELEASE, __HIP_MEMORY_SCOPE_AGENT);
    if (blockIdx.x == 0){
      for (;;){
        unsigned s = 0;
        #pragma unroll
        for (int i = 0; i < 8; ++i)
          s += __hip_atomic_load(&ctl[i*32], __ATOMIC_ACQUIRE, __HIP_MEMORY_SCOPE_AGENT);
        if (s >= (ord + 1u) * NBLK) break;
        __builtin_amdgcn_s_sleep(2);
      }
      __hip_atomic_store(&ctl[256], ord + 1u, __ATOMIC_RELEASE, __HIP_MEMORY_SCOPE_AGENT);
    } else {
      while (__hip_atomic_load(&ctl[256], __ATOMIC_ACQUIRE, __HIP_MEMORY_SCOPE_AGENT) < ord + 1u)
        __builtin_amdgcn_s_sleep(2);
    }
    __threadfence();
  }
  __syncthreads();
}

// half-block (128-thread) sum; red has 4 slots; ALL 256 threads must call
__device__ inline float hsum(float v, float* red){
  v += __shfl_xor(v,1);  v += __shfl_xor(v,2);  v += __shfl_xor(v,4);
  v += __shfl_xor(v,8);  v += __shfl_xor(v,16); v += __shfl_xor(v,32);
  int w = threadIdx.x >> 6;
  __syncthreads();
  if ((threadIdx.x & 63) == 0) red[w] = v;
  __syncthreads();
  int h = (threadIdx.x >> 7) << 1;
  return red[h] + red[h+1];
}

// ------- weights fp32->bf16 + inner transposes + qkv bias pack (1 launch) --
__global__ __launch_bounds__(256) void wcvt(
  const float* conv, const float* Wq, const float* Wk, const float* Wv,
  const float* Wo, const float* W1, const float* W2,
  const float* in_w, const float* out_w, const float* f1w, const float* f2w,
  const float* bq, const float* bk, const float* bv,
  ushort_t* dc, ushort_t* dqkv, ushort_t* dout, ushort_t* d1, ushort_t* d2,
  float* t_in, float* t_out, float* t_f1, float* t_f2, float* bqkv)
{
  if (blockIdx.x >= 4680){                  // transpose/pack tail
    int idx = (blockIdx.x-4680)*256 + threadIdx.x;
    if (idx < 384*128){ int j=idx>>7, k=idx&127; t_in[k*384+j]=in_w[idx]; }
    if (idx < 128*128){ int j=idx>>7, k=idx&127;
      t_out[k*128+j]=out_w[idx]; t_f1[k*128+j]=f1w[idx]; t_f2[k*128+j]=f2w[idx]; }
    if (idx < NLY*128){ int l=idx>>7, j=idx&127;
      bqkv[l*384+j]=bq[idx]; bqkv[l*384+128+j]=bk[idx]; bqkv[l*384+256+j]=bv[idx]; }
    return;
  }
  long i = 4l*((long)blockIdx.x*256 + threadIdx.x);
  if (i < 3612672l){
    float4 f = *reinterpret_cast<const float4*>(conv+i);
    dc[i]=f2bf(f.x); dc[i+1]=f2bf(f.y); dc[i+2]=f2bf(f.z); dc[i+3]=f2bf(f.w);
    return;
  }
  if (i < 3907584l){                       // Wq | Wk | Wv  ->  (L,384,128)
    long o = i - 3612672l;
    int  seg = (int)(o / 98304l);
    long off = o - (long)seg*98304l;
    long layer = off >> 14, rem = off & 16383l;
    const float* s = (seg==0) ? Wq : (seg==1) ? Wk : Wv;
    float4 f = *reinterpret_cast<const float4*>(s+off);
    long dst = layer*49152l + (long)seg*16384l + rem;
    dqkv[dst]=f2bf(f.x); dqkv[dst+1]=f2bf(f.y); dqkv[dst+2]=f2bf(f.z); dqkv[dst+3]=f2bf(f.w);
    return;
  }
  const float* s; ushort_t* d; long off;
  if      (i < 4005888l){ s=Wo; d=dout; off=i-3907584l; }
  else if (i < 4399104l){ s=W1; d=d1;   off=i-4005888l; }
  else                  { s=W2; d=d2;   off=i-4399104l; }
  float4 f = *reinterpret_cast<const float4*>(s+off);
  d[off]=f2bf(f.x); d[off+1]=f2bf(f.y); d[off+2]=f2bf(f.z); d[off+3]=f2bf(f.w);
}

// ---------------- patch embed: split-K into NZ disjoint slabs --------------
__global__ __launch_bounds__(256) void patch_gemm(
  const float* __restrict__ A, const ushort_t* __restrict__ Wb, float* __restrict__ C)
{
  __shared__ __align__(16) ushort_t As[32*64];
  __shared__ __align__(16) ushort_t Ws[128*64];
  const int tid = threadIdx.x, lane = tid & 63, wid = tid >> 6;
  const int wr = wid & 1, wc = wid >> 1;
  const int m0 = blockIdx.x * 32;
  const int kbase = blockIdx.z * 1344;
  float* Cz = C + (size_t)blockIdx.z * NBT * EE;
  f32x4 acc[4];
  #pragma unroll
  for (int j=0;j<4;j++) acc[j] = (f32x4){0.f,0.f,0.f,0.f};

  for (int kt = 0; kt < 21; ++kt){
    int k0 = kbase + kt*64;
    { int r = tid >> 3, kq = (tid & 7) * 8;
      const float* src = A + (size_t)(m0+r)*KP + k0 + kq;
      float4 f0 = *reinterpret_cast<const float4*>(src);
      float4 f1 = *reinterpret_cast<const float4*>(src+4);
      us8 o;
      o[0]=f2bf(f0.x); o[1]=f2bf(f0.y); o[2]=f2bf(f0.z); o[3]=f2bf(f0.w);
      o[4]=f2bf(f1.x); o[5]=f2bf(f1.y); o[6]=f2bf(f1.z); o[7]=f2bf(f1.w);
      *reinterpret_cast<us8*>(&As[r*64 + (kq ^ ((r&7)<<3))]) = o;
    }
    #pragma unroll
    for (int i=0;i<4;i++){
      int rr = (tid>>3) + 32*i, kq = (tid & 7) * 8;
      us8 v = *reinterpret_cast<const us8*>(Wb + (size_t)rr*KP + k0 + kq);
      *reinterpret_cast<us8*>(&Ws[rr*64 + (kq ^ ((rr&7)<<3))]) = v;
    }
    __syncthreads();
    #pragma unroll
    for (int ks=0; ks<2; ++ks){
      int ar = wr*16 + (lane&15);
      int kb = ks*32 + (lane>>4)*8;
      bf16x8 a = *reinterpret_cast<const bf16x8*>(&As[ar*64 + (kb ^ ((ar&7)<<3))]);
      #pragma unroll
      for (int j=0;j<4;j++){
        int nn = wc*64 + j*16 + (lane&15);
        bf16x8 b = *reinterpret_cast<const bf16x8*>(&Ws[nn*64 + (kb ^ ((nn&7)<<3))]);
        acc[j] = __builtin_amdgcn_mfma_f32_16x16x32_bf16(a, b, acc[j], 0,0,0);
      }
    }
    __syncthreads();
  }
  #pragma unroll
  for (int j=0;j<4;j++)
    #pragma unroll
    for (int rr=0;rr<4;rr++){
      int row = m0 + wr*16 + (lane>>4)*4 + rr;
      int col = wc*64 + j*16 + (lane&15);
      Cz[row*EE + col] = acc[j][rr];
    }
}

// =========================== THE MEGAKERNEL ================================
__global__ __launch_bounds__(256, 2) void mega(
  const float* __restrict__ part, const float* __restrict__ ctok,
  const float* __restrict__ t_in, const float* __restrict__ in_b,
  const float* __restrict__ t_out, const float* __restrict__ out_b,
  const float* __restrict__ i1g, const float* __restrict__ i1b,
  const float* __restrict__ i2g, const float* __restrict__ i2b,
  const float* __restrict__ t_f1, const float* __restrict__ fb1,
  const float* __restrict__ t_f2, const float* __restrict__ fb2,
  const float* __restrict__ rtgs, const int* __restrict__ actions,
  const int* __restrict__ tsteps, const float* __restrict__ ret_w,
  const float* __restrict__ ret_b, const float* __restrict__ act_tab,
  const float* __restrict__ pos_emb, const float* __restrict__ gpos,
  const ushort_t* __restrict__ Wqkvb, const float* __restrict__ bqkv,
  const float* __restrict__ ln1g, const float* __restrict__ ln1b,
  const ushort_t* __restrict__ Wob, const float* __restrict__ bo,
  const float* __restrict__ ln2g, const float* __restrict__ ln2b,
  const ushort_t* __restrict__ W1b, const float* __restrict__ b1v,
  const ushort_t* __restrict__ W2b, const float* __restrict__ b2v,
  const float* __restrict__ lnfg, const float* __restrict__ lnfb,
  const float* __restrict__ head_w,
  float* __restrict__ semb, float* __restrict__ x,
  ushort_t* __restrict__ qkvb, ushort_t* __restrict__ yb,
  float* __restrict__ out, unsigned* __restrict__ ctl)
{
  __shared__ __align__(16) char sm[73728];
  const int tid = threadIdx.x, bid = blockIdx.x;
  const int lane = tid & 63, wid = tid >> 6;
  unsigned ord = 0;

  // ============ phase: inner TIT -> semb (2 tokens per block per iter) =====
  {
    float* X  = (float*)sm;           // [2 half][2 t][128]
    float* H  = X  + 512;
    float* Q  = H  + 512;
    float* K2 = Q  + 512;
    float* V  = K2 + 512;
    float* red = V + 512;             // [4]
    const int half = tid >> 7, e = tid & 127, so = half*256;
    for (int it = 0; it < 2; ++it){
      if (it*1024 + bid*2 >= NBT) break;       // uniform per block
      int bt = it*1024 + bid*2 + half;
      {
        float acc = 0;
        #pragma unroll
        for (int z = 0; z < NZ; ++z) acc += part[(size_t)z*NBT*EE + bt*128 + e];
        X[so + e]       = ctok[e];
        X[so + 128 + e] = acc;
      }
      __syncthreads();
      for (int t=0;t<2;t++){                   // LN1
        float xv = X[so+t*128+e];
        float m = hsum(xv, red)*(1.f/128.f);
        float d = xv - m;
        float var = hsum(d*d, red)*(1.f/128.f);
        H[so+t*128+e] = d*rsqrtf(var+1e-5f)*i1g[e] + i1b[e];
      }
      __syncthreads();
      for (int t=0;t<2;t++){                   // qkv
        float aq=in_b[e], ak=in_b[128+e], av=in_b[256+e];
        for (int kk=0;kk<128;kk++){
          float h = H[so+t*128+kk];
          aq += h*t_in[kk*384+e]; ak += h*t_in[kk*384+128+e]; av += h*t_in[kk*384+256+e];
        }
        Q[so+t*128+e]=aq; K2[so+t*128+e]=ak; V[so+t*128+e]=av;
      }
      __syncthreads();
      const float sc = 0.08838834764831845f;
      float s00 = hsum(Q[so+e]*K2[so+e], red)*sc;
      float s01 = hsum(Q[so+e]*K2[so+128+e], red)*sc;
      float s10 = hsum(Q[so+128+e]*K2[so+e], red)*sc;
      float s11 = hsum(Q[so+128+e]*K2[so+128+e], red)*sc;
      {
        float m0 = fmaxf(s00,s01), p0=__expf(s00-m0), p1=__expf(s01-m0), iv=1.f/(p0+p1);
        H[so+e] = (p0*V[so+e] + p1*V[so+128+e])*iv;
        float m1 = fmaxf(s10,s11), r0=__expf(s10-m1), r1=__expf(s11-m1), iw=1.f/(r0+r1);
        H[so+128+e] = (r0*V[so+e] + r1*V[so+128+e])*iw;
      }
      __syncthreads();
      for (int t=0;t<2;t++){                   // out-proj + residual
        float o = out_b[e];
        for (int kk=0;kk<128;kk++) o += H[so+t*128+kk]*t_out[kk*128+e];
        X[so+t*128+e] += o;
      }
      __syncthreads();
      for (int t=0;t<2;t++){                   // LN2 -> Q
        float xv = X[so+t*128+e];
        float m = hsum(xv, red)*(1.f/128.f);
        float d = xv - m;
        float var = hsum(d*d, red)*(1.f/128.f);
        Q[so+t*128+e] = d*rsqrtf(var+1e-5f)*i2g[e] + i2b[e];
      }
      __syncthreads();
      for (int t=0;t<2;t++){                   // FFN1 relu -> H
        float a = fb1[e];
        for (int kk=0;kk<128;kk++) a += Q[so+t*128+kk]*t_f1[kk*128+e];
        H[so+t*128+e] = fmaxf(a, 0.f);
      }
      __syncthreads();
      for (int t=0;t<2;t++){                   // FFN2 + residual
        float a = fb2[e];
        for (int kk=0;kk<128;kk++) a += H[so+t*128+kk]*t_f2[kk*128+e];
        X[so+t*128+e] += a;
      }
      semb[(size_t)bt*128 + e] = X[so+e];
      __syncthreads();
    }
  }
  gbar(ctl, ord++);

  // ============ phase: build token stream x ================================
  for (int idx = bid*256 + tid; idx < NS*EE; idx += NBLK*256){
    int e = idx & 127, s = idx >> 7;
    int b = s / LTK, p = s - b*LTK;
    int t = p/3, m = p - 3*t;
    float tok;
    if      (m == 0) tok = tanhf(rtgs[b*NT+t]*ret_w[e] + ret_b[e]);
    else if (m == 1) tok = semb[(size_t)(b*NT+t)*128 + e];
    else             tok = tanhf(act_tab[actions[b*NT+t+1]*128 + e]);
    x[idx] = tok + gpos[(size_t)tsteps[b]*128 + e] + pos_emb[p*128 + e];
  }
  gbar(ctl, ord++);

  // ============ 6 outer layers =============================================
  for (int L = 0; L < NLY; ++L){
    // ---- phase A: LN1 + QKV (267 units of 64 rows x 128-col seg) ----
    {
      ushort_t* ab  = (ushort_t*)sm;            // [64][128] swz
      ushort_t* wbs = (ushort_t*)(sm + 16384);  // [128][128] swz
      const float* lng = ln1g + L*128;
      const float* lnb = ln1b + L*128;
      for (int u = bid; u < 267; u += NBLK){
        int mt = u/3, seg = u - 3*mt, m0 = mt*64;
        { int r = tid>>2, q = tid&3;              // 4 threads/row, 32 elems
          const float* src = x + (size_t)(m0+r)*128 + q*32;
          float xv[32];
          #pragma unroll
          for (int i=0;i<8;i++){
            float4 f = *reinterpret_cast<const float4*>(src + 4*i);
            xv[4*i]=f.x; xv[4*i+1]=f.y; xv[4*i+2]=f.z; xv[4*i+3]=f.w;
          }
          float s = 0;
          #pragma unroll
          for (int i=0;i<32;i++) s += xv[i];
          s += __shfl_xor(s,1); s += __shfl_xor(s,2);
          float mean = s * (1.0f/128.0f);
          float vs = 0;
          #pragma unroll
          for (int i=0;i<32;i++){ float d = xv[i]-mean; vs += d*d; }
          vs += __shfl_xor(vs,1); vs += __shfl_xor(vs,2);
          float rstd = rsqrtf(vs*(1.0f/128.0f) + 1e-5f);
          int sw = (r&7)<<3;
          #pragma unroll
          for (int g=0; g<4; ++g){
            int c0 = q*32 + g*8;
            us8 o;
            #pragma unroll
            for (int j=0;j<8;j++) o[j] = f2bf((xv[g*8+j]-mean)*rstd*lng[c0+j] + lnb[c0+j]);
            *reinterpret_cast<us8*>(&ab[r*128 + (c0 ^ sw)]) = o;
          }
        }
        { int rr = tid>>1, hf = tid&1;
          const ushort_t* src = Wqkvb + (size_t)L*49152 + (size_t)(seg*128+rr)*128 + hf*64;
          int sw = (rr&7)<<3;
          #pragma unroll
          for (int g=0; g<8; ++g)
            *reinterpret_cast<us8*>(&wbs[rr*128 + ((hf*64+g*8) ^ sw)]) =
              *reinterpret_cast<const us8*>(src + g*8);
        }
        __syncthreads();
        int arow = wid*16 + (lane&15), asw = (arow&7)<<3;
        #pragma unroll
        for (int nt=0; nt<8; ++nt){
          f32x4 acc = (f32x4){0.f,0.f,0.f,0.f};
          int nrow = nt*16 + (lane&15), nsw = (nrow&7)<<3;
          #pragma unroll
          for (int ks=0; ks<4; ++ks){
            int kb = ks*32 + (lane>>4)*8;
            bf16x8 a = *reinterpret_cast<const bf16x8*>(&ab[arow*128 + (kb ^ asw)]);
            bf16x8 b = *reinterpret_cast<const bf16x8*>(&wbs[nrow*128 + (kb ^ nsw)]);
            acc = __builtin_amdgcn_mfma_f32_16x16x32_bf16(a, b, acc, 0,0,0);
          }
          int col = nt*16 + (lane&15);
          float bia = bqkv[L*384 + seg*128 + col];
          #pragma unroll
          for (int rr=0; rr<4; ++rr){
            int row = wid*16 + (lane>>4)*4 + rr;
            qkvb[(size_t)(m0+row)*384 + seg*128 + col] = f2bf(acc[rr] + bia);
          }
        }
        __syncthreads();
      }
    }
    gbar(ctl, ord++);

    // ---- phase B: attention, unit = (b,h) = bid ----
    {
      float* qs = (float*)sm;        // [89][20]
      float* ks = qs + 1780;
      float* vs = ks + 1780;
      float* ps = vs + 1780;         // [89][91]
      int b = bid >> 3, h = bid & 7;
      for (int i = tid; i < LTK*16; i += 256){
        int rr = i >> 4, d = i & 15;
        size_t g = (size_t)(b*LTK+rr)*384 + h*16 + d;
        qs[rr*20+d] = bf2f(qkvb[g]);
        ks[rr*20+d] = bf2f(qkvb[g+128]);
        vs[rr*20+d] = bf2f(qkvb[g+256]);
      }
      __syncthreads();
      for (int i = tid; i < LTK*LTK; i += 256){
        int t = i/LTK, u = i - t*LTK;
        if (u <= t){
          const float4* qv = (const float4*)&qs[t*20];
          const float4* kv = (const float4*)&ks[u*20];
          float s = 0;
          #pragma unroll
          for (int d4=0; d4<4; ++d4){
            float4 a = qv[d4], c = kv[d4];
            s += a.x*c.x + a.y*c.y + a.z*c.z + a.w*c.w;
          }
          ps[t*91+u] = s*0.25f;
        }
      }
      __syncthreads();
      if (tid < LTK){
        int t = tid;
        float mx = -1e30f;
        for (int u=0;u<=t;u++) mx = fmaxf(mx, ps[t*91+u]);
        float l = 0;
        for (int u=0;u<=t;u++){ float p = __expf(ps[t*91+u]-mx); ps[t*91+u]=p; l+=p; }
        ps[t*91+89] = 1.0f/l;
      }
      __syncthreads();
      for (int i = tid; i < LTK*16; i += 256){
        int t = i >> 4, d = i & 15;
        float a = 0;
        for (int u=0; u<=t; ++u) a += ps[t*91+u]*vs[u*20+d];
        yb[(size_t)(b*LTK+t)*128 + h*16 + d] = f2bf(a*ps[t*91+89]);
      }
      __syncthreads();
    }
    gbar(ctl, ord++);

    // ---- phase C: Wo+res+LN2+FFN (178 units of 32 rows) ----
    {
      ushort_t* wbs = (ushort_t*)sm;            // 32 KB
      ushort_t* ys  = (ushort_t*)(sm + 32768);  // 8 KB  [32][128] swz
      float*    xr  = (float*)(sm + 40960);     // [32][136] fp32
      ushort_t* h2  = (ushort_t*)(sm + 65536);  // 8 KB  [32][128] swz
      ushort_t* f1  = (ushort_t*)(sm + 32768);  // [32][512] swz (reuses ys+xr)
      for (int u = bid; u < 178; u += NBLK){
        int m0 = u*32;
        { int rr = tid>>3, q = tid&7, sw = (rr&7)<<3;
          const ushort_t* src = yb + (size_t)(m0+rr)*128 + q*16;
          *reinterpret_cast<us8*>(&ys[rr*128 + ((q*16)   ^ sw)]) = *reinterpret_cast<const us8*>(src);
          *reinterpret_cast<us8*>(&ys[rr*128 + ((q*16+8) ^ sw)]) = *reinterpret_cast<const us8*>(src+8);
        }
        { int rr = tid>>1, hf = tid&1, sw = (rr&7)<<3;
          const ushort_t* src = Wob + (size_t)L*16384 + rr*128 + hf*64;
          #pragma unroll
          for (int g=0; g<8; ++g)
            *reinterpret_cast<us8*>(&wbs[rr*128 + ((hf*64+g*8) ^ sw)]) =
              *reinterpret_cast<const us8*>(src + g*8);
        }
        __syncthreads();
        { int arow = (wid&1)*16 + (lane&15), asw = (arow&7)<<3;
          #pragma unroll
          for (int nt4=0; nt4<4; ++nt4){
            int nt = (wid>>1)*4 + nt4;
            f32x4 acc = (f32x4){0.f,0.f,0.f,0.f};
            int nrow = nt*16 + (lane&15), nsw = (nrow&7)<<3;
            #pragma unroll
            for (int ks=0; ks<4; ++ks){
              int kb = ks*32 + (lane>>4)*8;
              bf16x8 a = *reinterpret_cast<const bf16x8*>(&ys[arow*128 + (kb ^ asw)]);
              bf16x8 b = *reinterpret_cast<const bf16x8*>(&wbs[nrow*128 + (kb ^ nsw)]);
              acc = __builtin_amdgcn_mfma_f32_16x16x32_bf16(a, b, acc, 0,0,0);
            }
            int col = nt*16 + (lane&15);
            float bia = bo[L*128 + col];
            #pragma unroll
            for (int rr=0; rr<4; ++rr){
              int row = (wid&1)*16 + (lane>>4)*4 + rr;
              float v = acc[rr] + bia + x[(size_t)(m0+row)*128 + col];
              x[(size_t)(m0+row)*128 + col] = v;
              xr[row*136 + col] = v;
            }
          }
        }
        __syncthreads();
        { int r = tid>>3, q = tid&7;              // LN2: 8 threads/row
          float xv[16];
          #pragma unroll
          for (int i=0;i<16;i++) xv[i] = xr[r*136 + q*16 + i];
          float s = 0;
          #pragma unroll
          for (int i=0;i<16;i++) s += xv[i];
          s += __shfl_xor(s,1); s += __shfl_xor(s,2); s += __shfl_xor(s,4);
          float mean = s * (1.0f/128.0f);
          float vs = 0;
          #pragma unroll
          for (int i=0;i<16;i++){ float d = xv[i]-mean; vs += d*d; }
          vs += __shfl_xor(vs,1); vs += __shfl_xor(vs,2); vs += __shfl_xor(vs,4);
          float rstd = rsqrtf(vs*(1.0f/128.0f) + 1e-5f);
          int sw = (r&7)<<3;
          #pragma unroll
          for (int g=0; g<2; ++g){
            us8 o;
            #pragma unroll
            for (int j=0;j<8;j++){
              int c = q*16 + g*8 + j;
              o[j] = f2bf((xv[g*8+j]-mean)*rstd*ln2g[L*128+c] + ln2b[L*128+c]);
            }
            *reinterpret_cast<us8*>(&h2[r*128 + ((q*16+g*8) ^ sw)]) = o;
          }
        }
        // FFN1: f1 = gelu(h2 @ W1^T + b1), 4 col chunks
        for (int c=0; c<4; ++c){
          __syncthreads();
          { int rr = tid>>1, hf = tid&1, sw = (rr&7)<<3;
            const ushort_t* src = W1b + (size_t)L*65536 + (size_t)(c*128+rr)*128 + hf*64;
            #pragma unroll
            for (int g=0; g<8; ++g)
              *reinterpret_cast<us8*>(&wbs[rr*128 + ((hf*64+g*8) ^ sw)]) =
                *reinterpret_cast<const us8*>(src + g*8);
          }
          __syncthreads();
          int arow = (wid&1)*16 + (lane&15), asw = (arow&7)<<3;
          #pragma unroll
          for (int nt4=0; nt4<4; ++nt4){
            int nt = (wid>>1)*4 + nt4;
            f32x4 acc = (f32x4){0.f,0.f,0.f,0.f};
            int nrow = nt*16 + (lane&15), nsw = (nrow&7)<<3;
            #pragma unroll
            for (int ks=0; ks<4; ++ks){
              int kb = ks*32 + (lane>>4)*8;
              bf16x8 a = *reinterpret_cast<const bf16x8*>(&h2[arow*128 + (kb ^ asw)]);
              bf16x8 b = *reinterpret_cast<const bf16x8*>(&wbs[nrow*128 + (kb ^ nsw)]);
              acc = __builtin_amdgcn_mfma_f32_16x16x32_bf16(a, b, acc, 0,0,0);
            }
            int colg = c*128 + nt*16 + (lane&15);
            float bia = b1v[L*512 + colg];
            #pragma unroll
            for (int rr=0; rr<4; ++rr){
              int row = (wid&1)*16 + (lane>>4)*4 + rr;
              float v = acc[rr] + bia;
              v = 0.5f*v*(1.0f + erff(v*0.70710678118654752f));
              f1[row*512 + (colg ^ ((row&7)<<3))] = f2bf(v);
            }
          }
        }
        // FFN2: x += f1 @ W2^T + b2
        f32x4 acc2[4];
        #pragma unroll
        for (int nt4=0; nt4<4; ++nt4) acc2[nt4] = (f32x4){0.f,0.f,0.f,0.f};
        for (int c=0; c<4; ++c){
          __syncthreads();
          { int rr = tid>>1, hf = tid&1, sw = (rr&7)<<3;
            const ushort_t* src = W2b + (size_t)L*65536 + (size_t)rr*512 + c*128 + hf*64;
            #pragma unroll
            for (int g=0; g<8; ++g)
              *reinterpret_cast<us8*>(&wbs[rr*128 + ((hf*64+g*8) ^ sw)]) =
                *reinterpret_cast<const us8*>(src + g*8);
          }
          __syncthreads();
          int arow = (wid&1)*16 + (lane&15), asw = (arow&7)<<3;
          #pragma unroll
          for (int nt4=0; nt4<4; ++nt4){
            int nt = (wid>>1)*4 + nt4;
            int nrow = nt*16 + (lane&15), nsw = (nrow&7)<<3;
            #pragma unroll
            for (int ks=0; ks<4; ++ks){
              int kb = ks*32 + (lane>>4)*8;
              bf16x8 a = *reinterpret_cast<const bf16x8*>(&f1[arow*512 + ((c*128+kb) ^ asw)]);
              bf16x8 b = *reinterpret_cast<const bf16x8*>(&wbs[nrow*128 + (kb ^ nsw)]);
              acc2[nt4] = __builtin_amdgcn_mfma_f32_16x16x32_bf16(a, b, acc2[nt4], 0,0,0);
            }
          }
        }
        { 
          #pragma unroll
          for (int nt4=0; nt4<4; ++nt4){
            int nt = (wid>>1)*4 + nt4, col = nt*16 + (lane&15);
            float bia = b2v[L*128 + col];
            #pragma unroll
            for (int rr=0; rr<4; ++rr){
              int row = (wid&1)*16 + (lane>>4)*4 + rr;
              x[(size_t)(m0+row)*128 + col] += acc2[nt4][rr] + bia;
            }
          }
        }
        __syncthreads();
      }
    }
    gbar(ctl, ord++);
  }

  // ============ phase: final LN + head (2 tokens/block/iter) ===============
  {
    float* hsm = (float*)sm;          // [2][128]
    float* red = hsm + 256;           // [4]
    const int half = tid >> 7, e = tid & 127;
    for (int it = 0; it < 2; ++it){
      if (it*1024 + bid*2 >= NBT) break;
      int bt = it*1024 + bid*2 + half;
      int b = bt/NT, t = bt - b*NT;
      const float* row = x + (size_t)(b*LTK + 3*t + 1)*128;
      float xv = row[e];
      float m = hsum(xv, red)*(1.f/128.f);
      float d = xv - m;
      float var = hsum(d*d, red)*(1.f/128.f);
      hsm[half*128+e] = d*rsqrtf(var+1e-5f)*lnfg[e] + lnfb[e];
      __syncthreads();
      int wv = (tid>>6)&1, ln = tid&63;
      #pragma unroll
      for (int oo=0; oo<9; ++oo){
        int o = wv*9 + oo;
        float s = hsm[half*128+ln]*head_w[o*128+ln] + hsm[half*128+ln+64]*head_w[o*128+ln+64];
        s += __shfl_xor(s,1); s += __shfl_xor(s,2); s += __shfl_xor(s,4);
        s += __shfl_xor(s,8); s += __shfl_xor(s,16); s += __shfl_xor(s,32);
        if (ln == 0) out[(size_t)bt*NV + o] = s;
      }
      __syncthreads();
    }
  }
}

// ===========================================================================
extern "C" void kernel_launch(void* const* d_in, const int* in_sizes, int n_in,
                              void* d_out, int out_size, void* d_ws, size_t ws_size,
                              hipStream_t stream)
{
  const float* states  = (const float*)d_in[0];
  const int*   actions = (const int*)  d_in[1];
  const float* rtgs    = (const float*)d_in[2];
  const int*   tsteps  = (const int*)  d_in[3];
  const float* conv_w  = (const float*)d_in[4];
  const float* ctok    = (const float*)d_in[5];
  const float* in_w    = (const float*)d_in[6];
  const float* in_b    = (const float*)d_in[7];
  const float* out_w   = (const float*)d_in[8];
  const float* out_b   = (const float*)d_in[9];
  const float* i1g     = (const float*)d_in[10];
  const float* i1b     = (const float*)d_in[11];
  const float* i2g     = (const float*)d_in[12];
  const float* i2b     = (const float*)d_in[13];
  const float* fw1     = (const float*)d_in[14];
  const float* fb1     = (const float*)d_in[15];
  const float* fw2     = (const float*)d_in[16];
  const float* fb2     = (const float*)d_in[17];
  const float* ret_w   = (const float*)d_in[18];
  const float* ret_b   = (const float*)d_in[19];
  const float* act_tab = (const float*)d_in[20];
  const float* pos_emb = (const float*)d_in[21];
  const float* gpos    = (const float*)d_in[22];
  const float* ln1g    = (const float*)d_in[23];
  const float* ln1b    = (const float*)d_in[24];
  const float* Wq      = (const float*)d_in[25];
  const float* bq      = (const float*)d_in[26];
  const float* Wk      = (const float*)d_in[27];
  const float* bk      = (const float*)d_in[28];
  const float* Wv      = (const float*)d_in[29];
  const float* bv      = (const float*)d_in[30];
  const float* Wo      = (const float*)d_in[31];
  const float* bo      = (const float*)d_in[32];
  const float* ln2g    = (const float*)d_in[33];
  const float* ln2b    = (const float*)d_in[34];
  const float* W1      = (const float*)d_in[35];
  const float* b1      = (const float*)d_in[36];
  const float* W2      = (const float*)d_in[37];
  const float* b2      = (const float*)d_in[38];
  const float* lnfg    = (const float*)d_in[39];
  const float* lnfb    = (const float*)d_in[40];
  const float* head_w  = (const float*)d_in[41];

  char* w = (char*)d_ws;
  size_t off = 0;
  auto alloc = [&](size_t bytes)->char* {
    char* p = w + off; off += (bytes + 255) & ~(size_t)255; return p;
  };
  float*    part  = (float*)   alloc((size_t)NZ*NBT*EE*4);
  float*    semb  = (float*)   alloc((size_t)NBT*EE*4);
  float*    x     = (float*)   alloc((size_t)NS*EE*4);
  ushort_t* qkvb  = (ushort_t*)alloc((size_t)NS*384*2);
  ushort_t* yb    = (ushort_t*)alloc((size_t)NS*EE*2);
  ushort_t* cwb   = (ushort_t*)alloc((size_t)EE*KP*2);
  ushort_t* Wqkvb = (ushort_t*)alloc((size_t)NLY*384*128*2);
  ushort_t* Wob   = (ushort_t*)alloc((size_t)NLY*128*128*2);
  ushort_t* W1b   = (ushort_t*)alloc((size_t)NLY*512*128*2);
  ushort_t* W2b   = (ushort_t*)alloc((size_t)NLY*128*512*2);
  float*    t_in  = (float*)   alloc(384*128*4);
  float*    t_out = (float*)   alloc(128*128*4);
  float*    t_f1  = (float*)   alloc(128*128*4);
  float*    t_f2  = (float*)   alloc(128*128*4);
  float*    bqkv  = (float*)   alloc(NLY*384*4);
  unsigned* ctl   = (unsigned*)alloc(4096);
  (void)in_sizes; (void)n_in; (void)out_size; (void)ws_size;

  hipMemsetAsync(ctl, 0, 4096, stream);
  wcvt<<<4872,256,0,stream>>>(conv_w,Wq,Wk,Wv,Wo,W1,W2,
                              in_w,out_w,fw1,fw2, bq,bk,bv,
                              cwb,Wqkvb,Wob,W1b,W2b,
                              t_in,t_out,t_f1,t_f2, bqkv);
  patch_gemm<<<dim3(60,1,NZ),256,0,stream>>>(states, cwb, part);
  mega<<<NBLK,256,0,stream>>>(part, ctok, t_in, in_b, t_out, out_b,
                              i1g,i1b,i2g,i2b, t_f1,fb1, t_f2,fb2,
                              rtgs, actions, tsteps, ret_w, ret_b, act_tab,
                              pos_emb, gpos,
                              Wqkvb, bqkv, ln1g, ln1b,
                              Wob, bo, ln2g, ln2b,
                              W1b, b1, W2b, b2,
                              lnfg, lnfb, head_w,
                              semb, x, qkvb, yb, (float*)d_out, ctl);
}

// Round 5
// 414.567 us; speedup vs baseline: 11.9567x; 11.9567x over previous
//
#include <hip/hip_runtime.h>

#define NB   64
#define NT   30
#define NBT  1920        // NB*NT
#define EE   128
#define KP   28224       // 4*84*84
#define LTK  89          // 3*NT-1
#define NS   5696        // NB*LTK
#define NLY  6
#define NV   18
#define NZ   21          // split-K slabs for patch gemm

typedef unsigned short ushort_t;
using bf16x8 = __attribute__((ext_vector_type(8))) short;
using us8    = __attribute__((ext_vector_type(8))) unsigned short;
using f32x4  = __attribute__((ext_vector_type(4))) float;
using f32x16 = __attribute__((ext_vector_type(16))) float;

__device__ inline ushort_t f2bf(float f){
  union { float f; unsigned u; } v; v.f = f;
  unsigned r = v.u + 0x7FFFu + ((v.u >> 16) & 1u);   // RNE
  return (ushort_t)(r >> 16);
}
__device__ inline float bf2f(ushort_t h){
  union { unsigned u; float f; } v; v.u = ((unsigned)h) << 16; return v.f;
}

// ------- weights fp32->bf16 + inner transposes + qkv bias pack (1 launch) --
__global__ __launch_bounds__(256) void wcvt(
  const float* conv, const float* Wq, const float* Wk, const float* Wv,
  const float* Wo, const float* W1, const float* W2,
  const float* in_w, const float* out_w, const float* f1w, const float* f2w,
  const float* bq, const float* bk, const float* bv,
  ushort_t* dc, ushort_t* dqkv, ushort_t* dout, ushort_t* d1, ushort_t* d2,
  float* t_in, float* t_out, float* t_f1, float* t_f2, float* bqkv)
{
  if (blockIdx.x >= 4680){                  // transpose/pack tail
    int idx = (blockIdx.x-4680)*256 + threadIdx.x;
    if (idx < 384*128){ int j=idx>>7, k=idx&127; t_in[k*384+j]=in_w[idx]; }
    if (idx < 128*128){ int j=idx>>7, k=idx&127;
      t_out[k*128+j]=out_w[idx]; t_f1[k*128+j]=f1w[idx]; t_f2[k*128+j]=f2w[idx]; }
    if (idx < NLY*128){ int l=idx>>7, j=idx&127;
      bqkv[l*384+j]=bq[idx]; bqkv[l*384+128+j]=bk[idx]; bqkv[l*384+256+j]=bv[idx]; }
    return;
  }
  long i = 4l*((long)blockIdx.x*256 + threadIdx.x);
  if (i < 3612672l){
    float4 f = *reinterpret_cast<const float4*>(conv+i);
    dc[i]=f2bf(f.x); dc[i+1]=f2bf(f.y); dc[i+2]=f2bf(f.z); dc[i+3]=f2bf(f.w);
    return;
  }
  if (i < 3907584l){                       // Wq | Wk | Wv  ->  (L,384,128)
    long o = i - 3612672l;
    int  seg = (int)(o / 98304l);
    long off = o - (long)seg*98304l;
    long layer = off >> 14, rem = off & 16383l;
    const float* s = (seg==0) ? Wq : (seg==1) ? Wk : Wv;
    float4 f = *reinterpret_cast<const float4*>(s+off);
    long dst = layer*49152l + (long)seg*16384l + rem;
    dqkv[dst]=f2bf(f.x); dqkv[dst+1]=f2bf(f.y); dqkv[dst+2]=f2bf(f.z); dqkv[dst+3]=f2bf(f.w);
    return;
  }
  const float* s; ushort_t* d; long off;
  if      (i < 4005888l){ s=Wo; d=dout; off=i-3907584l; }
  else if (i < 4399104l){ s=W1; d=d1;   off=i-4005888l; }
  else                  { s=W2; d=d2;   off=i-4399104l; }
  float4 f = *reinterpret_cast<const float4*>(s+off);
  d[off]=f2bf(f.x); d[off+1]=f2bf(f.y); d[off+2]=f2bf(f.z); d[off+3]=f2bf(f.w);
}

// ---------------- patch embed: split-K into NZ disjoint slabs --------------
__global__ __launch_bounds__(256) void patch_gemm(
  const float* __restrict__ A, const ushort_t* __restrict__ Wb, float* __restrict__ C)
{
  __shared__ __align__(16) ushort_t As[32*64];
  __shared__ __align__(16) ushort_t Ws[128*64];
  const int tid = threadIdx.x, lane = tid & 63, wid = tid >> 6;
  const int wr = wid & 1, wc = wid >> 1;
  const int m0 = blockIdx.x * 32;
  const int kbase = blockIdx.z * 1344;
  float* Cz = C + (size_t)blockIdx.z * NBT * EE;
  f32x4 acc[4];
  #pragma unroll
  for (int j=0;j<4;j++) acc[j] = (f32x4){0.f,0.f,0.f,0.f};

  for (int kt = 0; kt < 21; ++kt){
    int k0 = kbase + kt*64;
    { int r = tid >> 3, kq = (tid & 7) * 8;
      const float* src = A + (size_t)(m0+r)*KP + k0 + kq;
      float4 f0 = *reinterpret_cast<const float4*>(src);
      float4 f1 = *reinterpret_cast<const float4*>(src+4);
      us8 o;
      o[0]=f2bf(f0.x); o[1]=f2bf(f0.y); o[2]=f2bf(f0.z); o[3]=f2bf(f0.w);
      o[4]=f2bf(f1.x); o[5]=f2bf(f1.y); o[6]=f2bf(f1.z); o[7]=f2bf(f1.w);
      *reinterpret_cast<us8*>(&As[r*64 + (kq ^ ((r&7)<<3))]) = o;
    }
    #pragma unroll
    for (int i=0;i<4;i++){
      int rr = (tid>>3) + 32*i, kq = (tid & 7) * 8;
      us8 v = *reinterpret_cast<const us8*>(Wb + (size_t)rr*KP + k0 + kq);
      *reinterpret_cast<us8*>(&Ws[rr*64 + (kq ^ ((rr&7)<<3))]) = v;
    }
    __syncthreads();
    #pragma unroll
    for (int ks=0; ks<2; ++ks){
      int ar = wr*16 + (lane&15);
      int kb = ks*32 + (lane>>4)*8;
      bf16x8 a = *reinterpret_cast<const bf16x8*>(&As[ar*64 + (kb ^ ((ar&7)<<3))]);
      #pragma unroll
      for (int j=0;j<4;j++){
        int nn = wc*64 + j*16 + (lane&15);
        bf16x8 b = *reinterpret_cast<const bf16x8*>(&Ws[nn*64 + (kb ^ ((nn&7)<<3))]);
        acc[j] = __builtin_amdgcn_mfma_f32_16x16x32_bf16(a, b, acc[j], 0,0,0);
      }
    }
    __syncthreads();
  }
  #pragma unroll
  for (int j=0;j<4;j++)
    #pragma unroll
    for (int rr=0;rr<4;rr++){
      int row = m0 + wr*16 + (lane>>4)*4 + rr;
      int col = wc*64 + j*16 + (lane&15);
      Cz[row*EE + col] = acc[j][rr];
    }
}

// ---------------- block-of-128 reduction helper ----------------------------
__device__ inline float bsum128(float v, volatile float* red){
  v += __shfl_xor(v,1);  v += __shfl_xor(v,2);  v += __shfl_xor(v,4);
  v += __shfl_xor(v,8);  v += __shfl_xor(v,16); v += __shfl_xor(v,32);
  int tid = threadIdx.x;
  if ((tid & 63) == 0) red[tid>>6] = v;
  __syncthreads();
  float s = red[0] + red[1];
  __syncthreads();
  return s;
}

// ---------------- inner TIT (one block per bt, 128 threads) ----------------
__global__ __launch_bounds__(128) void inner_tit(
  const float* __restrict__ part, const float* __restrict__ ctok,
  const float* __restrict__ t_in, const float* __restrict__ in_b,
  const float* __restrict__ t_out, const float* __restrict__ out_b,
  const float* __restrict__ g1, const float* __restrict__ b1_,
  const float* __restrict__ g2, const float* __restrict__ b2_,
  const float* __restrict__ t_f1, const float* __restrict__ fb1,
  const float* __restrict__ t_f2, const float* __restrict__ fb2,
  float* __restrict__ semb)
{
  int bt = blockIdx.x, e = threadIdx.x;
  __shared__ float xs[2][128], hs[2][128], qs[2][128], ks2[2][128], vs[2][128];
  __shared__ float red[2];
  {
    float acc = 0;
    #pragma unroll
    for (int z=0; z<NZ; ++z) acc += part[(size_t)z*NBT*EE + bt*128 + e];
    xs[0][e] = ctok[e];
    xs[1][e] = acc;
  }
  __syncthreads();
  for (int t=0;t<2;t++){
    float xv = xs[t][e];
    float m = bsum128(xv, red)*(1.f/128.f);
    float d = xv - m;
    float var = bsum128(d*d, red)*(1.f/128.f);
    hs[t][e] = d*rsqrtf(var+1e-5f)*g1[e] + b1_[e];
  }
  __syncthreads();
  for (int t=0;t<2;t++){
    float aq=in_b[e], ak=in_b[128+e], av=in_b[256+e];
    for (int kk=0;kk<128;kk++){
      float h = hs[t][kk];
      aq += h*t_in[kk*384+e]; ak += h*t_in[kk*384+128+e]; av += h*t_in[kk*384+256+e];
    }
    qs[t][e]=aq; ks2[t][e]=ak; vs[t][e]=av;
  }
  __syncthreads();
  const float sc = 0.08838834764831845f;
  float s00 = bsum128(qs[0][e]*ks2[0][e], red)*sc;
  float s01 = bsum128(qs[0][e]*ks2[1][e], red)*sc;
  float s10 = bsum128(qs[1][e]*ks2[0][e], red)*sc;
  float s11 = bsum128(qs[1][e]*ks2[1][e], red)*sc;
  {
    float m0 = fmaxf(s00,s01), p0=__expf(s00-m0), p1=__expf(s01-m0), iv=1.f/(p0+p1);
    hs[0][e] = (p0*vs[0][e] + p1*vs[1][e])*iv;
    float m1 = fmaxf(s10,s11), r0=__expf(s10-m1), r1=__expf(s11-m1), iw=1.f/(r0+r1);
    hs[1][e] = (r0*vs[0][e] + r1*vs[1][e])*iw;
  }
  __syncthreads();
  for (int t=0;t<2;t++){
    float o = out_b[e];
    for (int kk=0;kk<128;kk++) o += hs[t][kk]*t_out[kk*128+e];
    xs[t][e] += o;
  }
  __syncthreads();
  for (int t=0;t<2;t++){
    float xv = xs[t][e];
    float m = bsum128(xv, red)*(1.f/128.f);
    float d = xv - m;
    float var = bsum128(d*d, red)*(1.f/128.f);
    qs[t][e] = d*rsqrtf(var+1e-5f)*g2[e] + b2_[e];
  }
  __syncthreads();
  for (int t=0;t<2;t++){
    float a = fb1[e];
    for (int kk=0;kk<128;kk++) a += qs[t][kk]*t_f1[kk*128+e];
    hs[t][e] = fmaxf(a, 0.f);
  }
  __syncthreads();
  for (int t=0;t<2;t++){
    float a = fb2[e];
    for (int kk=0;kk<128;kk++) a += hs[t][kk]*t_f2[kk*128+e];
    xs[t][e] += a;
  }
  semb[bt*128+e] = xs[0][e];
}

// ---------------- token interleave + positional ----------------------------
__global__ __launch_bounds__(256) void build_tok(
  const float* __restrict__ semb, const float* __restrict__ rtgs,
  const int* __restrict__ actions, const int* __restrict__ tsteps,
  const float* __restrict__ ret_w, const float* __restrict__ ret_b,
  const float* __restrict__ act_tab, const float* __restrict__ pos_emb,
  const float* __restrict__ gpos, float* __restrict__ x)
{
  int idx = blockIdx.x*256 + threadIdx.x;
  if (idx >= NS*EE) return;
  int e = idx & 127, s = idx >> 7;
  int b = s / LTK, p = s - b*LTK;
  int t = p/3, m = p - 3*t;
  float tok;
  if      (m == 0) tok = tanhf(rtgs[b*NT+t]*ret_w[e] + ret_b[e]);
  else if (m == 1) tok = semb[(b*NT+t)*128 + e];
  else             tok = tanhf(act_tab[actions[b*NT+t+1]*128 + e]);
  x[idx] = tok + gpos[(size_t)tsteps[b]*128 + e] + pos_emb[p*128 + e];
}

// ======== fused attention: one block per (b,h); LN1+QKV(h)+attn -> y =======
__global__ __launch_bounds__(256, 2) void attn_fused(
  const float* __restrict__ x, const ushort_t* __restrict__ Wqkv,
  const float* __restrict__ bqkv, const float* __restrict__ lng,
  const float* __restrict__ lnb, ushort_t* __restrict__ y)
{
  __shared__ __align__(16) char sm[69504];
  ushort_t* ab  = (ushort_t*)sm;              // [96][128] bf16 swz (24576)
  ushort_t* wb  = (ushort_t*)(sm + 24576);    // [48][128] bf16 swz (12288)
  float*    S   = (float*)sm;                 // [96][97] f32 (37248) union ab/wb
  ushort_t* qa  = (ushort_t*)(sm + 37248);    // [96][22] bf16
  ushort_t* ka  = (ushort_t*)(sm + 41472);    // [96][22]
  ushort_t* vta = (ushort_t*)(sm + 45696);    // [16][108] V^T
  ushort_t* pb  = (ushort_t*)(sm + 49152);    // [96][104]
  float*    inv = (float*)(sm + 69120);       // [96]

  const int b = blockIdx.x >> 3, h = blockIdx.x & 7;
  const int tid = threadIdx.x, lane = tid & 63, wid = tid >> 6;

  // ---- phase 0: LN1 -> ab (2 threads/row); stage wb (48 head rows) ----
  if (tid < 192){
    int row = tid >> 1, half = tid & 1;
    int sw = (row&7)<<3;
    if (row < LTK){
      const float* src = x + (size_t)(b*LTK+row)*128 + half*64;
      float xv[64];
      #pragma unroll
      for (int i=0;i<16;i++){
        float4 f = *reinterpret_cast<const float4*>(src + 4*i);
        xv[4*i]=f.x; xv[4*i+1]=f.y; xv[4*i+2]=f.z; xv[4*i+3]=f.w;
      }
      float s = 0;
      #pragma unroll
      for (int i=0;i<64;i++) s += xv[i];
      s += __shfl_xor(s,1);
      float mean = s*(1.0f/128.0f);
      float vs = 0;
      #pragma unroll
      for (int i=0;i<64;i++){ float d = xv[i]-mean; vs += d*d; }
      vs += __shfl_xor(vs,1);
      float rstd = rsqrtf(vs*(1.0f/128.0f) + 1e-5f);
      #pragma unroll
      for (int g=0; g<8; ++g){
        int k = half*64 + g*8;
        us8 o;
        #pragma unroll
        for (int j=0;j<8;j++) o[j] = f2bf((xv[g*8+j]-mean)*rstd*lng[k+j] + lnb[k+j]);
        *reinterpret_cast<us8*>(&ab[row*128 + (k ^ sw)]) = o;
      }
    } else {
      #pragma unroll
      for (int g=0; g<8; ++g)
        *reinterpret_cast<us8*>(&ab[row*128 + ((half*64+g*8) ^ sw)]) = (us8){0,0,0,0,0,0,0,0};
    }
  }
  for (int idx = tid; idx < 384; idx += 256){   // wb: 48 rows x 128
    int rr = idx >> 3, c = (idx & 7) * 16;
    int seg = rr >> 4, n = rr & 15;
    const ushort_t* src = Wqkv + (size_t)(seg*128 + h*16 + n)*128 + c;
    int sw = (rr&7)<<3;
    *reinterpret_cast<us8*>(&wb[rr*128 + ( c    ^ sw)]) = *reinterpret_cast<const us8*>(src);
    *reinterpret_cast<us8*>(&wb[rr*128 + ((c+8) ^ sw)]) = *reinterpret_cast<const us8*>(src+8);
  }
  __syncthreads();

  // ---- phase 1: QKV gemm (96x48, K=128) -> qa, ka, vta ----
  for (int idx = wid; idx < 18; idx += 4){
    int rt = idx / 3, nt = idx - 3*(idx/3);
    f32x4 acc = (f32x4){0.f,0.f,0.f,0.f};
    int arow = rt*16 + (lane&15), asw = (arow&7)<<3;
    int nrow = nt*16 + (lane&15), nsw = (nrow&7)<<3;
    #pragma unroll
    for (int ks=0; ks<4; ++ks){
      int kb = ks*32 + (lane>>4)*8;
      bf16x8 a = *reinterpret_cast<const bf16x8*>(&ab[arow*128 + (kb ^ asw)]);
      bf16x8 bf = *reinterpret_cast<const bf16x8*>(&wb[nrow*128 + (kb ^ nsw)]);
      acc = __builtin_amdgcn_mfma_f32_16x16x32_bf16(a, bf, acc, 0,0,0);
    }
    int d = lane & 15;
    float bia = bqkv[nt*128 + h*16 + d];
    #pragma unroll
    for (int rr=0; rr<4; ++rr){
      int rg = rt*16 + (lane>>4)*4 + rr;
      ushort_t hv = f2bf(acc[rr] + bia);
      if      (nt == 0) qa[rg*22 + d] = hv;
      else if (nt == 1) ka[rg*22 + d] = hv;
      else              vta[d*108 + rg] = hv;
    }
  }
  __syncthreads();

  // ---- phase 2: S = Q K^T * 0.25 (lower-tri 32x32 tiles) ----
  {
    static const int TR[6] = {0,1,1,2,2,2};
    static const int TC[6] = {0,0,1,0,1,2};
    for (int idx = wid; idx < 6; idx += 4){
      int R = TR[idx], C = TC[idx];
      int arow = R*32 + (lane&31), brow = C*32 + (lane&31);
      int ke = (lane>>5)*8;
      bf16x8 a  = *reinterpret_cast<const bf16x8*>(&qa[arow*22 + ke]);
      bf16x8 bf = *reinterpret_cast<const bf16x8*>(&ka[brow*22 + ke]);
      f32x16 sc = {};
      sc = __builtin_amdgcn_mfma_f32_32x32x16_bf16(a, bf, sc, 0,0,0);
      #pragma unroll
      for (int r=0; r<16; ++r){
        int rin = (r&3) + 8*(r>>2) + 4*(lane>>5);
        S[(R*32+rin)*97 + C*32 + (lane&31)] = sc[r]*0.25f;
      }
    }
  }
  __syncthreads();

  // ---- phase 3: softmax rows -> pb (bf16), inv ----
  if (tid < 192){
    int t = tid >> 1, half = tid & 1;
    int u0 = half*48;
    float mx = -1e30f;
    if (t < LTK){
      for (int u=u0; u<u0+48; ++u) if (u<=t) mx = fmaxf(mx, S[t*97+u]);
    }
    mx = fmaxf(mx, __shfl_xor(mx,1));
    float smv = 0;
    if (t < LTK){
      for (int u=u0; u<u0+48; ++u){
        float p = 0;
        if (u<=t){ p = __expf(S[t*97+u]-mx); smv += p; }
        pb[t*104+u] = f2bf(p);
      }
    } else {
      for (int u=u0; u<u0+48; ++u) pb[t*104+u] = 0;
    }
    smv += __shfl_xor(smv,1);
    if (half==0) inv[t] = (t<LTK) ? 1.0f/smv : 0.0f;
  }
  __syncthreads();

  // ---- phase 4: O = P V -> y ----
  for (int rt = wid; rt < 6; rt += 4){
    int arow = rt*16 + (lane&15);
    f32x4 acc = (f32x4){0.f,0.f,0.f,0.f};
    #pragma unroll
    for (int ks=0; ks<3; ++ks){
      int kb = ks*32 + (lane>>4)*8;
      bf16x8 a  = *reinterpret_cast<const bf16x8*>(&pb[arow*104 + kb]);
      bf16x8 bf = *reinterpret_cast<const bf16x8*>(&vta[(lane&15)*108 + kb]);
      acc = __builtin_amdgcn_mfma_f32_16x16x32_bf16(a, bf, acc, 0,0,0);
    }
    #pragma unroll
    for (int rr=0; rr<4; ++rr){
      int rg = rt*16 + (lane>>4)*4 + rr;
      if (rg < LTK)
        y[(size_t)(b*LTK+rg)*128 + h*16 + (lane&15)] = f2bf(acc[rr]*inv[rg]);
    }
  }
}

// ======== fused FFN: Wo+res -> LN2 -> FFN1(gelu) -> FFN2+res [-> head] =====
template<bool HEAD>
__global__ __launch_bounds__(256) void ffn_fused(
  const ushort_t* __restrict__ yg, const ushort_t* __restrict__ Wo,
  const float* __restrict__ bo, const float* __restrict__ g2,
  const float* __restrict__ b2g, const ushort_t* __restrict__ W1,
  const float* __restrict__ b1v, const ushort_t* __restrict__ W2,
  const float* __restrict__ b2v, float* __restrict__ x,
  const float* __restrict__ lnfg, const float* __restrict__ lnfb,
  const float* __restrict__ hw, float* __restrict__ out)
{
  __shared__ __align__(16) char sm[99328];
  ushort_t* wbs = (ushort_t*)sm;             // [128][128] swz (32768)
  ushort_t* ys  = (ushort_t*)(sm + 32768);   // [32][128] swz (8192)
  float*    xr  = (float*)(sm + 40960);      // [32][136] f32 (17408)
  ushort_t* h2  = (ushort_t*)(sm + 58368);   // [32][128] swz (8192)
  ushort_t* f1  = (ushort_t*)(sm + 66560);   // [32][512] swz (32768)
  const int tid = threadIdx.x, lane = tid & 63, wid = tid >> 6;
  const int m0 = blockIdx.x * 32;

  // ---- phase A: o = y@Wo^T + bo + x -> xr ; LN2 -> h2 ----
  { int rr = tid>>3, q = tid&7, sw = (rr&7)<<3;
    const ushort_t* src = yg + (size_t)(m0+rr)*128 + q*16;
    *reinterpret_cast<us8*>(&ys[rr*128 + ((q*16)   ^ sw)]) = *reinterpret_cast<const us8*>(src);
    *reinterpret_cast<us8*>(&ys[rr*128 + ((q*16+8) ^ sw)]) = *reinterpret_cast<const us8*>(src+8);
  }
  { int rr = tid>>1, hf = tid&1, sw = (rr&7)<<3;
    const ushort_t* src = Wo + (size_t)rr*128 + hf*64;
    #pragma unroll
    for (int g=0; g<8; ++g)
      *reinterpret_cast<us8*>(&wbs[rr*128 + ((hf*64+g*8) ^ sw)]) =
        *reinterpret_cast<const us8*>(src + g*8);
  }
  __syncthreads();
  { int arow = (wid&1)*16 + (lane&15), asw = (arow&7)<<3;
    #pragma unroll
    for (int nt4=0; nt4<4; ++nt4){
      int nt = (wid>>1)*4 + nt4;
      f32x4 acc = (f32x4){0.f,0.f,0.f,0.f};
      int nrow = nt*16 + (lane&15), nsw = (nrow&7)<<3;
      #pragma unroll
      for (int ks=0; ks<4; ++ks){
        int kb = ks*32 + (lane>>4)*8;
        bf16x8 a = *reinterpret_cast<const bf16x8*>(&ys[arow*128 + (kb ^ asw)]);
        bf16x8 b = *reinterpret_cast<const bf16x8*>(&wbs[nrow*128 + (kb ^ nsw)]);
        acc = __builtin_amdgcn_mfma_f32_16x16x32_bf16(a, b, acc, 0,0,0);
      }
      int col = nt*16 + (lane&15);
      float bia = bo[col];
      #pragma unroll
      for (int rr=0; rr<4; ++rr){
        int row = (wid&1)*16 + (lane>>4)*4 + rr;
        xr[row*136 + col] = acc[rr] + bia + x[(size_t)(m0+row)*128 + col];
      }
    }
  }
  __syncthreads();
  { int r = tid>>3, q = tid&7;              // LN2: 8 threads/row
    float xv[16];
    #pragma unroll
    for (int i=0;i<16;i++) xv[i] = xr[r*136 + q*16 + i];
    float s = 0;
    #pragma unroll
    for (int i=0;i<16;i++) s += xv[i];
    s += __shfl_xor(s,1); s += __shfl_xor(s,2); s += __shfl_xor(s,4);
    float mean = s * (1.0f/128.0f);
    float vs = 0;
    #pragma unroll
    for (int i=0;i<16;i++){ float d = xv[i]-mean; vs += d*d; }
    vs += __shfl_xor(vs,1); vs += __shfl_xor(vs,2); vs += __shfl_xor(vs,4);
    float rstd = rsqrtf(vs*(1.0f/128.0f) + 1e-5f);
    int sw = (r&7)<<3;
    #pragma unroll
    for (int g=0; g<2; ++g){
      us8 o;
      #pragma unroll
      for (int j=0;j<8;j++){
        int c = q*16 + g*8 + j;
        o[j] = f2bf((xv[g*8+j]-mean)*rstd*g2[c] + b2g[c]);
      }
      *reinterpret_cast<us8*>(&h2[r*128 + ((q*16+g*8) ^ sw)]) = o;
    }
  }

  // ---- phase B: f1 = gelu(h2 @ W1^T + b1) ----
  for (int c=0; c<4; ++c){
    __syncthreads();
    { int rr = tid>>1, hf = tid&1, sw = (rr&7)<<3;
      const ushort_t* src = W1 + (size_t)(c*128+rr)*128 + hf*64;
      #pragma unroll
      for (int g=0; g<8; ++g)
        *reinterpret_cast<us8*>(&wbs[rr*128 + ((hf*64+g*8) ^ sw)]) =
          *reinterpret_cast<const us8*>(src + g*8);
    }
    __syncthreads();
    int arow = (wid&1)*16 + (lane&15), asw = (arow&7)<<3;
    #pragma unroll
    for (int nt4=0; nt4<4; ++nt4){
      int nt = (wid>>1)*4 + nt4;
      f32x4 acc = (f32x4){0.f,0.f,0.f,0.f};
      int nrow = nt*16 + (lane&15), nsw = (nrow&7)<<3;
      #pragma unroll
      for (int ks=0; ks<4; ++ks){
        int kb = ks*32 + (lane>>4)*8;
        bf16x8 a = *reinterpret_cast<const bf16x8*>(&h2[arow*128 + (kb ^ asw)]);
        bf16x8 b = *reinterpret_cast<const bf16x8*>(&wbs[nrow*128 + (kb ^ nsw)]);
        acc = __builtin_amdgcn_mfma_f32_16x16x32_bf16(a, b, acc, 0,0,0);
      }
      int colg = c*128 + nt*16 + (lane&15);
      float bia = b1v[colg];
      #pragma unroll
      for (int rr=0; rr<4; ++rr){
        int row = (wid&1)*16 + (lane>>4)*4 + rr;
        float v = acc[rr] + bia;
        v = 0.5f*v*(1.0f + erff(v*0.70710678118654752f));
        f1[row*512 + (colg ^ ((row&7)<<3))] = f2bf(v);
      }
    }
  }

  // ---- phase C: final = xr + f1 @ W2^T + b2 ----
  f32x4 acc2[4];
  #pragma unroll
  for (int nt4=0; nt4<4; ++nt4) acc2[nt4] = (f32x4){0.f,0.f,0.f,0.f};
  for (int c=0; c<4; ++c){
    __syncthreads();
    { int rr = tid>>1, hf = tid&1, sw = (rr&7)<<3;
      const ushort_t* src = W2 + (size_t)rr*512 + c*128 + hf*64;
      #pragma unroll
      for (int g=0; g<8; ++g)
        *reinterpret_cast<us8*>(&wbs[rr*128 + ((hf*64+g*8) ^ sw)]) =
          *reinterpret_cast<const us8*>(src + g*8);
    }
    __syncthreads();
    int arow = (wid&1)*16 + (lane&15), asw = (arow&7)<<3;
    #pragma unroll
    for (int nt4=0; nt4<4; ++nt4){
      int nt = (wid>>1)*4 + nt4;
      int nrow = nt*16 + (lane&15), nsw = (nrow&7)<<3;
      #pragma unroll
      for (int ks=0; ks<4; ++ks){
        int kb = ks*32 + (lane>>4)*8;
        bf16x8 a = *reinterpret_cast<const bf16x8*>(&f1[arow*512 + ((c*128+kb) ^ asw)]);
        bf16x8 b = *reinterpret_cast<const bf16x8*>(&wbs[nrow*128 + (kb ^ nsw)]);
        acc2[nt4] = __builtin_amdgcn_mfma_f32_16x16x32_bf16(a, b, acc2[nt4], 0,0,0);
      }
    }
  }
  {
    #pragma unroll
    for (int nt4=0; nt4<4; ++nt4){
      int nt = (wid>>1)*4 + nt4, col = nt*16 + (lane&15);
      float bia = b2v[col];
      #pragma unroll
      for (int rr=0; rr<4; ++rr){
        int row = (wid&1)*16 + (lane>>4)*4 + rr;
        float v = acc2[nt4][rr] + bia + xr[row*136 + col];
        if constexpr (HEAD) xr[row*136 + col] = v;
        else                x[(size_t)(m0+row)*128 + col] = v;
      }
    }
  }
  if constexpr (HEAD){
    __syncthreads();
    for (int r = wid; r < 32; r += 4){
      int s = m0 + r, b = s / LTK, p = s - b*LTK;
      if (p % 3 != 1) continue;
      int t = p / 3;
      float v1 = xr[r*136 + lane];
      float v2 = xr[r*136 + 64 + lane];
      float sum = v1 + v2;
      sum += __shfl_xor(sum,1); sum += __shfl_xor(sum,2); sum += __shfl_xor(sum,4);
      sum += __shfl_xor(sum,8); sum += __shfl_xor(sum,16); sum += __shfl_xor(sum,32);
      float mean = sum*(1.0f/128.0f);
      float d1 = v1-mean, d2 = v2-mean;
      float var = d1*d1 + d2*d2;
      var += __shfl_xor(var,1); var += __shfl_xor(var,2); var += __shfl_xor(var,4);
      var += __shfl_xor(var,8); var += __shfl_xor(var,16); var += __shfl_xor(var,32);
      float rstd = rsqrtf(var*(1.0f/128.0f) + 1e-5f);
      float h1 = d1*rstd*lnfg[lane]    + lnfb[lane];
      float h2v= d2*rstd*lnfg[lane+64] + lnfb[lane+64];
      #pragma unroll
      for (int o=0; o<NV; ++o){
        float sdot = h1*hw[o*128+lane] + h2v*hw[o*128+lane+64];
        sdot += __shfl_xor(sdot,1); sdot += __shfl_xor(sdot,2); sdot += __shfl_xor(sdot,4);
        sdot += __shfl_xor(sdot,8); sdot += __shfl_xor(sdot,16); sdot += __shfl_xor(sdot,32);
        if (lane == 0) out[(size_t)(b*NT+t)*NV + o] = sdot;
      }
    }
  }
}

// ===========================================================================
extern "C" void kernel_launch(void* const* d_in, const int* in_sizes, int n_in,
                              void* d_out, int out_size, void* d_ws, size_t ws_size,
                              hipStream_t stream)
{
  const float* states  = (const float*)d_in[0];
  const int*   actions = (const int*)  d_in[1];
  const float* rtgs    = (const float*)d_in[2];
  const int*   tsteps  = (const int*)  d_in[3];
  const float* conv_w  = (const float*)d_in[4];
  const float* ctok    = (const float*)d_in[5];
  const float* in_w    = (const float*)d_in[6];
  const float* in_b    = (const float*)d_in[7];
  const float* out_w   = (const float*)d_in[8];
  const float* out_b   = (const float*)d_in[9];
  const float* i1g     = (const float*)d_in[10];
  const float* i1b     = (const float*)d_in[11];
  const float* i2g     = (const float*)d_in[12];
  const float* i2b     = (const float*)d_in[13];
  const float* fw1     = (const float*)d_in[14];
  const float* fb1     = (const float*)d_in[15];
  const float* fw2     = (const float*)d_in[16];
  const float* fb2     = (const float*)d_in[17];
  const float* ret_w   = (const float*)d_in[18];
  const float* ret_b   = (const float*)d_in[19];
  const float* act_tab = (const float*)d_in[20];
  const float* pos_emb = (const float*)d_in[21];
  const float* gpos    = (const float*)d_in[22];
  const float* ln1g    = (const float*)d_in[23];
  const float* ln1b    = (const float*)d_in[24];
  const float* Wq      = (const float*)d_in[25];
  const float* bq      = (const float*)d_in[26];
  const float* Wk      = (const float*)d_in[27];
  const float* bk      = (const float*)d_in[28];
  const float* Wv      = (const float*)d_in[29];
  const float* bv      = (const float*)d_in[30];
  const float* Wo      = (const float*)d_in[31];
  const float* bo      = (const float*)d_in[32];
  const float* ln2g    = (const float*)d_in[33];
  const float* ln2b    = (const float*)d_in[34];
  const float* W1      = (const float*)d_in[35];
  const float* b1      = (const float*)d_in[36];
  const float* W2      = (const float*)d_in[37];
  const float* b2      = (const float*)d_in[38];
  const float* lnfg    = (const float*)d_in[39];
  const float* lnfb    = (const float*)d_in[40];
  const float* head_w  = (const float*)d_in[41];

  char* w = (char*)d_ws;
  size_t off = 0;
  auto alloc = [&](size_t bytes)->char* {
    char* p = w + off; off += (bytes + 255) & ~(size_t)255; return p;
  };
  float*    part  = (float*)   alloc((size_t)NZ*NBT*EE*4);
  float*    semb  = (float*)   alloc((size_t)NBT*EE*4);
  float*    x     = (float*)   alloc((size_t)NS*EE*4);
  ushort_t* yb    = (ushort_t*)alloc((size_t)NS*EE*2);
  ushort_t* cwb   = (ushort_t*)alloc((size_t)EE*KP*2);
  ushort_t* Wqkvb = (ushort_t*)alloc((size_t)NLY*384*128*2);
  ushort_t* Wob   = (ushort_t*)alloc((size_t)NLY*128*128*2);
  ushort_t* W1b   = (ushort_t*)alloc((size_t)NLY*512*128*2);
  ushort_t* W2b   = (ushort_t*)alloc((size_t)NLY*128*512*2);
  float*    t_in  = (float*)   alloc(384*128*4);
  float*    t_out = (float*)   alloc(128*128*4);
  float*    t_f1  = (float*)   alloc(128*128*4);
  float*    t_f2  = (float*)   alloc(128*128*4);
  float*    bqkv  = (float*)   alloc(NLY*384*4);
  (void)in_sizes; (void)n_in; (void)out_size; (void)ws_size;

  wcvt<<<4872,256,0,stream>>>(conv_w,Wq,Wk,Wv,Wo,W1,W2,
                              in_w,out_w,fw1,fw2, bq,bk,bv,
                              cwb,Wqkvb,Wob,W1b,W2b,
                              t_in,t_out,t_f1,t_f2, bqkv);
  patch_gemm<<<dim3(60,1,NZ),256,0,stream>>>(states, cwb, part);
  inner_tit<<<NBT,128,0,stream>>>(part, ctok, t_in, in_b, t_out, out_b,
                                  i1g,i1b,i2g,i2b, t_f1,fb1, t_f2,fb2, semb);
  build_tok<<<2848,256,0,stream>>>(semb, rtgs, actions, tsteps, ret_w, ret_b,
                                   act_tab, pos_emb, gpos, x);
  for (int i=0;i<NLY;i++){
    attn_fused<<<512,256,0,stream>>>(
      x, Wqkvb+(size_t)i*49152, bqkv+(size_t)i*384, ln1g+i*128, ln1b+i*128, yb);
    if (i < NLY-1)
      ffn_fused<false><<<178,256,0,stream>>>(
        yb, Wob+(size_t)i*16384, bo+i*128, ln2g+i*128, ln2b+i*128,
        W1b+(size_t)i*65536, b1+i*512, W2b+(size_t)i*65536, b2+i*128, x,
        nullptr, nullptr, nullptr, nullptr);
    else
      ffn_fused<true><<<178,256,0,stream>>>(
        yb, Wob+(size_t)i*16384, bo+i*128, ln2g+i*128, ln2b+i*128,
        W1b+(size_t)i*65536, b1+i*512, W2b+(size_t)i*65536, b2+i*128, x,
        lnfg, lnfb, head_w, (float*)d_out);
  }
}

// Round 6
// 413.966 us; speedup vs baseline: 11.9740x; 1.0015x over previous
//
#include <hip/hip_runtime.h>

#define NB   64
#define NT   30
#define NBT  1920        // NB*NT
#define EE   128
#define KP   28224       // 4*84*84
#define LTK  89          // 3*NT-1
#define NS   5696        // NB*LTK
#define NLY  6
#define NV   18
#define NZ   21          // split-K slabs for patch gemm

typedef unsigned short ushort_t;
using bf16x8 = __attribute__((ext_vector_type(8))) short;
using us8    = __attribute__((ext_vector_type(8))) unsigned short;
using f32x4  = __attribute__((ext_vector_type(4))) float;
using f32x16 = __attribute__((ext_vector_type(16))) float;

__device__ inline ushort_t f2bf(float f){
  union { float f; unsigned u; } v; v.f = f;
  unsigned r = v.u + 0x7FFFu + ((v.u >> 16) & 1u);   // RNE
  return (ushort_t)(r >> 16);
}
__device__ inline float bf2f(ushort_t h){
  union { unsigned u; float f; } v; v.u = ((unsigned)h) << 16; return v.f;
}

// ------- weights fp32->bf16 + inner transposes + qkv bias pack (1 launch) --
__global__ __launch_bounds__(256) void wcvt(
  const float* conv, const float* Wq, const float* Wk, const float* Wv,
  const float* Wo, const float* W1, const float* W2,
  const float* in_w, const float* out_w, const float* f1w, const float* f2w,
  const float* bq, const float* bk, const float* bv,
  ushort_t* dc, ushort_t* dqkv, ushort_t* dout, ushort_t* d1, ushort_t* d2,
  float* t_in, float* t_out, float* t_f1, float* t_f2, float* bqkv)
{
  if (blockIdx.x >= 4680){                  // transpose/pack tail
    int idx = (blockIdx.x-4680)*256 + threadIdx.x;
    if (idx < 384*128){ int j=idx>>7, k=idx&127; t_in[k*384+j]=in_w[idx]; }
    if (idx < 128*128){ int j=idx>>7, k=idx&127;
      t_out[k*128+j]=out_w[idx]; t_f1[k*128+j]=f1w[idx]; t_f2[k*128+j]=f2w[idx]; }
    if (idx < NLY*128){ int l=idx>>7, j=idx&127;
      bqkv[l*384+j]=bq[idx]; bqkv[l*384+128+j]=bk[idx]; bqkv[l*384+256+j]=bv[idx]; }
    return;
  }
  long i = 4l*((long)blockIdx.x*256 + threadIdx.x);
  if (i < 3612672l){
    float4 f = *reinterpret_cast<const float4*>(conv+i);
    dc[i]=f2bf(f.x); dc[i+1]=f2bf(f.y); dc[i+2]=f2bf(f.z); dc[i+3]=f2bf(f.w);
    return;
  }
  if (i < 3907584l){                       // Wq | Wk | Wv  ->  (L,384,128)
    long o = i - 3612672l;
    int  seg = (int)(o / 98304l);
    long off = o - (long)seg*98304l;
    long layer = off >> 14, rem = off & 16383l;
    const float* s = (seg==0) ? Wq : (seg==1) ? Wk : Wv;
    float4 f = *reinterpret_cast<const float4*>(s+off);
    long dst = layer*49152l + (long)seg*16384l + rem;
    dqkv[dst]=f2bf(f.x); dqkv[dst+1]=f2bf(f.y); dqkv[dst+2]=f2bf(f.z); dqkv[dst+3]=f2bf(f.w);
    return;
  }
  const float* s; ushort_t* d; long off;
  if      (i < 4005888l){ s=Wo; d=dout; off=i-3907584l; }
  else if (i < 4399104l){ s=W1; d=d1;   off=i-4005888l; }
  else                  { s=W2; d=d2;   off=i-4399104l; }
  float4 f = *reinterpret_cast<const float4*>(s+off);
  d[off]=f2bf(f.x); d[off+1]=f2bf(f.y); d[off+2]=f2bf(f.z); d[off+3]=f2bf(f.w);
}

// -------- patch embed: BM=64, split-K into NZ disjoint slabs ---------------
__global__ __launch_bounds__(256) void patch_gemm(
  const float* __restrict__ A, const ushort_t* __restrict__ Wb, float* __restrict__ C)
{
  __shared__ __align__(16) ushort_t As[64*64];
  __shared__ __align__(16) ushort_t Ws[128*64];
  const int tid = threadIdx.x, lane = tid & 63, wid = tid >> 6;
  const int m0 = blockIdx.x * 64;
  const int kbase = blockIdx.z * 1344;
  float* Cz = C + (size_t)blockIdx.z * NBT * EE;
  f32x4 acc[8];
  #pragma unroll
  for (int j=0;j<8;j++) acc[j] = (f32x4){0.f,0.f,0.f,0.f};

  for (int kt = 0; kt < 21; ++kt){
    int k0 = kbase + kt*64;
    { // A stage: 64 rows x 64 cols fp32 -> bf16; 4 thr/row x 16 cols
      int r = tid >> 2, kq = (tid & 3) * 16, sw = (r&7)<<3;
      const float* src = A + (size_t)(m0+r)*KP + k0 + kq;
      us8 o0, o1;
      #pragma unroll
      for (int i=0;i<4;i++){
        float4 f = *reinterpret_cast<const float4*>(src + 4*i);
        ushort_t a0=f2bf(f.x), a1=f2bf(f.y), a2=f2bf(f.z), a3=f2bf(f.w);
        if (i<2){ o0[4*i]=a0; o0[4*i+1]=a1; o0[4*i+2]=a2; o0[4*i+3]=a3; }
        else    { o1[4*(i-2)]=a0; o1[4*(i-2)+1]=a1; o1[4*(i-2)+2]=a2; o1[4*(i-2)+3]=a3; }
      }
      *reinterpret_cast<us8*>(&As[r*64 + ( kq    ^ sw)]) = o0;
      *reinterpret_cast<us8*>(&As[r*64 + ((kq+8) ^ sw)]) = o1;
    }
    { // W stage: 128 rows x 64 cols bf16; 2 thr/row x 32 cols
      int rr = tid >> 1, kw = (tid & 1) * 32, sw = (rr&7)<<3;
      const ushort_t* src = Wb + (size_t)rr*KP + k0 + kw;
      #pragma unroll
      for (int g=0; g<4; ++g)
        *reinterpret_cast<us8*>(&Ws[rr*64 + ((kw+g*8) ^ sw)]) =
          *reinterpret_cast<const us8*>(src + g*8);
    }
    __syncthreads();
    #pragma unroll
    for (int ks=0; ks<2; ++ks){
      int arow = wid*16 + (lane&15);
      int kb = ks*32 + (lane>>4)*8;
      bf16x8 a = *reinterpret_cast<const bf16x8*>(&As[arow*64 + (kb ^ ((arow&7)<<3))]);
      #pragma unroll
      for (int nt=0; nt<8; ++nt){
        int nn = nt*16 + (lane&15);
        bf16x8 b = *reinterpret_cast<const bf16x8*>(&Ws[nn*64 + (kb ^ ((nn&7)<<3))]);
        acc[nt] = __builtin_amdgcn_mfma_f32_16x16x32_bf16(a, b, acc[nt], 0,0,0);
      }
    }
    __syncthreads();
  }
  #pragma unroll
  for (int nt=0; nt<8; ++nt)
    #pragma unroll
    for (int rr=0;rr<4;rr++){
      int row = m0 + wid*16 + (lane>>4)*4 + rr;
      int col = nt*16 + (lane&15);
      Cz[row*EE + col] = acc[nt][rr];
    }
}

// ---------------- block-of-128 reduction helper ----------------------------
__device__ inline float bsum128(float v, volatile float* red){
  v += __shfl_xor(v,1);  v += __shfl_xor(v,2);  v += __shfl_xor(v,4);
  v += __shfl_xor(v,8);  v += __shfl_xor(v,16); v += __shfl_xor(v,32);
  int tid = threadIdx.x;
  if ((tid & 63) == 0) red[tid>>6] = v;
  __syncthreads();
  float s = red[0] + red[1];
  __syncthreads();
  return s;
}

// ------- inner TIT (one block per bt) + token interleave + positional ------
__global__ __launch_bounds__(128) void inner_tit(
  const float* __restrict__ part, const float* __restrict__ ctok,
  const float* __restrict__ t_in, const float* __restrict__ in_b,
  const float* __restrict__ t_out, const float* __restrict__ out_b,
  const float* __restrict__ g1, const float* __restrict__ b1_,
  const float* __restrict__ g2, const float* __restrict__ b2_,
  const float* __restrict__ t_f1, const float* __restrict__ fb1,
  const float* __restrict__ t_f2, const float* __restrict__ fb2,
  const float* __restrict__ rtgs, const int* __restrict__ actions,
  const int* __restrict__ tsteps, const float* __restrict__ ret_w,
  const float* __restrict__ ret_b, const float* __restrict__ act_tab,
  const float* __restrict__ pos_emb, const float* __restrict__ gpos,
  float* __restrict__ x)
{
  int bt = blockIdx.x, e = threadIdx.x;
  __shared__ float xs[2][128], hs[2][128], qs[2][128], ks2[2][128], vs[2][128];
  __shared__ float red[2];
  {
    float acc = 0;
    #pragma unroll
    for (int z=0; z<NZ; ++z) acc += part[(size_t)z*NBT*EE + bt*128 + e];
    xs[0][e] = ctok[e];
    xs[1][e] = acc;
  }
  __syncthreads();
  for (int t=0;t<2;t++){
    float xv = xs[t][e];
    float m = bsum128(xv, red)*(1.f/128.f);
    float d = xv - m;
    float var = bsum128(d*d, red)*(1.f/128.f);
    hs[t][e] = d*rsqrtf(var+1e-5f)*g1[e] + b1_[e];
  }
  __syncthreads();
  for (int t=0;t<2;t++){
    float aq=in_b[e], ak=in_b[128+e], av=in_b[256+e];
    for (int kk=0;kk<128;kk++){
      float h = hs[t][kk];
      aq += h*t_in[kk*384+e]; ak += h*t_in[kk*384+128+e]; av += h*t_in[kk*384+256+e];
    }
    qs[t][e]=aq; ks2[t][e]=ak; vs[t][e]=av;
  }
  __syncthreads();
  const float sc = 0.08838834764831845f;
  float s00 = bsum128(qs[0][e]*ks2[0][e], red)*sc;
  float s01 = bsum128(qs[0][e]*ks2[1][e], red)*sc;
  float s10 = bsum128(qs[1][e]*ks2[0][e], red)*sc;
  float s11 = bsum128(qs[1][e]*ks2[1][e], red)*sc;
  {
    float m0 = fmaxf(s00,s01), p0=__expf(s00-m0), p1=__expf(s01-m0), iv=1.f/(p0+p1);
    hs[0][e] = (p0*vs[0][e] + p1*vs[1][e])*iv;
    float m1 = fmaxf(s10,s11), r0=__expf(s10-m1), r1=__expf(s11-m1), iw=1.f/(r0+r1);
    hs[1][e] = (r0*vs[0][e] + r1*vs[1][e])*iw;
  }
  __syncthreads();
  for (int t=0;t<2;t++){
    float o = out_b[e];
    for (int kk=0;kk<128;kk++) o += hs[t][kk]*t_out[kk*128+e];
    xs[t][e] += o;
  }
  __syncthreads();
  for (int t=0;t<2;t++){
    float xv = xs[t][e];
    float m = bsum128(xv, red)*(1.f/128.f);
    float d = xv - m;
    float var = bsum128(d*d, red)*(1.f/128.f);
    qs[t][e] = d*rsqrtf(var+1e-5f)*g2[e] + b2_[e];
  }
  __syncthreads();
  for (int t=0;t<2;t++){
    float a = fb1[e];
    for (int kk=0;kk<128;kk++) a += qs[t][kk]*t_f1[kk*128+e];
    hs[t][e] = fmaxf(a, 0.f);
  }
  __syncthreads();
  for (int t=0;t<2;t++){
    float a = fb2[e];
    for (int kk=0;kk<128;kk++) a += hs[t][kk]*t_f2[kk*128+e];
    xs[t][e] += a;
  }
  // ---- token interleave + positional: this block writes x rows 3t-1,3t,3t+1
  int b = bt / NT, t = bt - b*NT;
  float gp = gpos[(size_t)tsteps[b]*128 + e];
  x[((size_t)b*LTK + 3*t+1)*128 + e] = xs[0][e] + gp + pos_emb[(3*t+1)*128 + e];
  x[((size_t)b*LTK + 3*t  )*128 + e] =
      tanhf(rtgs[b*NT+t]*ret_w[e] + ret_b[e]) + gp + pos_emb[(3*t)*128 + e];
  if (t >= 1)
    x[((size_t)b*LTK + 3*t-1)*128 + e] =
        tanhf(act_tab[actions[b*NT+t]*128 + e]) + gp + pos_emb[(3*t-1)*128 + e];
}

// ======== fused attention: one block per (b,h); LN1+QKV(h)+attn -> y =======
__global__ __launch_bounds__(256, 2) void attn_fused(
  const float* __restrict__ x, const ushort_t* __restrict__ Wqkv,
  const float* __restrict__ bqkv, const float* __restrict__ lng,
  const float* __restrict__ lnb, ushort_t* __restrict__ y)
{
  __shared__ __align__(16) char sm[69504];
  ushort_t* ab  = (ushort_t*)sm;              // [96][128] bf16 swz (24576)
  ushort_t* wb  = (ushort_t*)(sm + 24576);    // [48][128] bf16 swz (12288)
  float*    S   = (float*)sm;                 // [96][97] f32 (37248) union ab/wb
  ushort_t* qa  = (ushort_t*)(sm + 37248);    // [96][22] bf16
  ushort_t* ka  = (ushort_t*)(sm + 41472);    // [96][22]
  ushort_t* vta = (ushort_t*)(sm + 45696);    // [16][108] V^T
  ushort_t* pb  = (ushort_t*)(sm + 49152);    // [96][104]
  float*    inv = (float*)(sm + 69120);       // [96]

  const int b = blockIdx.x >> 3, h = blockIdx.x & 7;
  const int tid = threadIdx.x, lane = tid & 63, wid = tid >> 6;

  // ---- phase 0: LN1 -> ab (2 threads/row); stage wb (48 head rows) ----
  if (tid < 192){
    int row = tid >> 1, half = tid & 1;
    int sw = (row&7)<<3;
    if (row < LTK){
      const float* src = x + (size_t)(b*LTK+row)*128 + half*64;
      float xv[64];
      #pragma unroll
      for (int i=0;i<16;i++){
        float4 f = *reinterpret_cast<const float4*>(src + 4*i);
        xv[4*i]=f.x; xv[4*i+1]=f.y; xv[4*i+2]=f.z; xv[4*i+3]=f.w;
      }
      float s = 0;
      #pragma unroll
      for (int i=0;i<64;i++) s += xv[i];
      s += __shfl_xor(s,1);
      float mean = s*(1.0f/128.0f);
      float vs = 0;
      #pragma unroll
      for (int i=0;i<64;i++){ float d = xv[i]-mean; vs += d*d; }
      vs += __shfl_xor(vs,1);
      float rstd = rsqrtf(vs*(1.0f/128.0f) + 1e-5f);
      #pragma unroll
      for (int g=0; g<8; ++g){
        int k = half*64 + g*8;
        us8 o;
        #pragma unroll
        for (int j=0;j<8;j++) o[j] = f2bf((xv[g*8+j]-mean)*rstd*lng[k+j] + lnb[k+j]);
        *reinterpret_cast<us8*>(&ab[row*128 + (k ^ sw)]) = o;
      }
    } else {
      #pragma unroll
      for (int g=0; g<8; ++g)
        *reinterpret_cast<us8*>(&ab[row*128 + ((half*64+g*8) ^ sw)]) = (us8){0,0,0,0,0,0,0,0};
    }
  }
  for (int idx = tid; idx < 384; idx += 256){   // wb: 48 rows x 128
    int rr = idx >> 3, c = (idx & 7) * 16;
    int seg = rr >> 4, n = rr & 15;
    const ushort_t* src = Wqkv + (size_t)(seg*128 + h*16 + n)*128 + c;
    int sw = (rr&7)<<3;
    *reinterpret_cast<us8*>(&wb[rr*128 + ( c    ^ sw)]) = *reinterpret_cast<const us8*>(src);
    *reinterpret_cast<us8*>(&wb[rr*128 + ((c+8) ^ sw)]) = *reinterpret_cast<const us8*>(src+8);
  }
  __syncthreads();

  // ---- phase 1: QKV gemm (96x48, K=128) -> qa, ka, vta ----
  for (int idx = wid; idx < 18; idx += 4){
    int rt = idx / 3, nt = idx - 3*(idx/3);
    f32x4 acc = (f32x4){0.f,0.f,0.f,0.f};
    int arow = rt*16 + (lane&15), asw = (arow&7)<<3;
    int nrow = nt*16 + (lane&15), nsw = (nrow&7)<<3;
    #pragma unroll
    for (int ks=0; ks<4; ++ks){
      int kb = ks*32 + (lane>>4)*8;
      bf16x8 a = *reinterpret_cast<const bf16x8*>(&ab[arow*128 + (kb ^ asw)]);
      bf16x8 bf = *reinterpret_cast<const bf16x8*>(&wb[nrow*128 + (kb ^ nsw)]);
      acc = __builtin_amdgcn_mfma_f32_16x16x32_bf16(a, bf, acc, 0,0,0);
    }
    int d = lane & 15;
    float bia = bqkv[nt*128 + h*16 + d];
    #pragma unroll
    for (int rr=0; rr<4; ++rr){
      int rg = rt*16 + (lane>>4)*4 + rr;
      ushort_t hv = f2bf(acc[rr] + bia);
      if      (nt == 0) qa[rg*22 + d] = hv;
      else if (nt == 1) ka[rg*22 + d] = hv;
      else              vta[d*108 + rg] = hv;
    }
  }
  __syncthreads();

  // ---- phase 2: S = Q K^T * 0.25 (lower-tri 32x32 tiles) ----
  {
    static const int TR[6] = {0,1,1,2,2,2};
    static const int TC[6] = {0,0,1,0,1,2};
    for (int idx = wid; idx < 6; idx += 4){
      int R = TR[idx], C = TC[idx];
      int arow = R*32 + (lane&31), brow = C*32 + (lane&31);
      int ke = (lane>>5)*8;
      bf16x8 a  = *reinterpret_cast<const bf16x8*>(&qa[arow*22 + ke]);
      bf16x8 bf = *reinterpret_cast<const bf16x8*>(&ka[brow*22 + ke]);
      f32x16 sc = {};
      sc = __builtin_amdgcn_mfma_f32_32x32x16_bf16(a, bf, sc, 0,0,0);
      #pragma unroll
      for (int r=0; r<16; ++r){
        int rin = (r&3) + 8*(r>>2) + 4*(lane>>5);
        S[(R*32+rin)*97 + C*32 + (lane&31)] = sc[r]*0.25f;
      }
    }
  }
  __syncthreads();

  // ---- phase 3: softmax rows -> pb (bf16), inv ----
  if (tid < 192){
    int t = tid >> 1, half = tid & 1;
    int u0 = half*48;
    float mx = -1e30f;
    if (t < LTK){
      for (int u=u0; u<u0+48; ++u) if (u<=t) mx = fmaxf(mx, S[t*97+u]);
    }
    mx = fmaxf(mx, __shfl_xor(mx,1));
    float smv = 0;
    if (t < LTK){
      for (int u=u0; u<u0+48; ++u){
        float p = 0;
        if (u<=t){ p = __expf(S[t*97+u]-mx); smv += p; }
        pb[t*104+u] = f2bf(p);
      }
    } else {
      for (int u=u0; u<u0+48; ++u) pb[t*104+u] = 0;
    }
    smv += __shfl_xor(smv,1);
    if (half==0) inv[t] = (t<LTK) ? 1.0f/smv : 0.0f;
  }
  __syncthreads();

  // ---- phase 4: O = P V -> y ----
  for (int rt = wid; rt < 6; rt += 4){
    int arow = rt*16 + (lane&15);
    f32x4 acc = (f32x4){0.f,0.f,0.f,0.f};
    #pragma unroll
    for (int ks=0; ks<3; ++ks){
      int kb = ks*32 + (lane>>4)*8;
      bf16x8 a  = *reinterpret_cast<const bf16x8*>(&pb[arow*104 + kb]);
      bf16x8 bf = *reinterpret_cast<const bf16x8*>(&vta[(lane&15)*108 + kb]);
      acc = __builtin_amdgcn_mfma_f32_16x16x32_bf16(a, bf, acc, 0,0,0);
    }
    #pragma unroll
    for (int rr=0; rr<4; ++rr){
      int rg = rt*16 + (lane>>4)*4 + rr;
      if (rg < LTK)
        y[(size_t)(b*LTK+rg)*128 + h*16 + (lane&15)] = f2bf(acc[rr]*inv[rg]);
    }
  }
}

// ======== fused FFN v2: dbuf 16KB weight chunks, interleaved FFN1/FFN2 =====
template<bool HEAD>
__global__ __launch_bounds__(256, 2) void ffn_fused(
  const ushort_t* __restrict__ yg, const ushort_t* __restrict__ Wo,
  const float* __restrict__ bo, const float* __restrict__ g2,
  const float* __restrict__ b2g, const ushort_t* __restrict__ W1,
  const float* __restrict__ b1v, const ushort_t* __restrict__ W2,
  const float* __restrict__ b2v, float* __restrict__ x,
  const float* __restrict__ lnfg, const float* __restrict__ lnfb,
  const float* __restrict__ hw, float* __restrict__ out)
{
  __shared__ __align__(16) char sm[66304];
  ushort_t* wbs = (ushort_t*)sm;             // [2][64][128] swz  32768
  float*    xr  = (float*)(sm + 32768);      // [32][132] f32    16896
  ushort_t* h2  = (ushort_t*)(sm + 49664);   // [32][128] swz     8192
  ushort_t* f1  = (ushort_t*)(sm + 57856);   // [32][128] swz     8192 (=ys in A)
  const int tid = threadIdx.x, lane = tid & 63, wid = tid >> 6;
  const int m0 = blockIdx.x * 32;

  // stage a 64x128 bf16 chunk (row stride `stride`) into wbs[buf]
  auto stageW = [&](const ushort_t* src_base, size_t stride, int buf){
    int rr = tid >> 2, q = tid & 3, sw = (rr&7)<<3;
    const ushort_t* s = src_base + (size_t)rr*stride + q*32;
    ushort_t* d = wbs + buf*8192 + rr*128;
    #pragma unroll
    for (int g=0; g<4; ++g)
      *reinterpret_cast<us8*>(&d[(q*32+g*8) ^ sw]) =
        *reinterpret_cast<const us8*>(s + g*8);
  };
  // 32-row x 64-col gemm vs wbs[buf]; wave wid -> col tile wid*16; acc[2] = rt 0,1
  auto gemmT = [&](const ushort_t* abuf, int buf, f32x4* accp){
    int nrow = wid*16 + (lane&15), nsw = (nrow&7)<<3;
    const ushort_t* wbp = wbs + buf*8192;
    #pragma unroll
    for (int rt=0; rt<2; ++rt){
      int arow = rt*16 + (lane&15), asw = (arow&7)<<3;
      #pragma unroll
      for (int ks=0; ks<4; ++ks){
        int kb = ks*32 + (lane>>4)*8;
        bf16x8 a = *reinterpret_cast<const bf16x8*>(&abuf[arow*128 + (kb ^ asw)]);
        bf16x8 bb = *reinterpret_cast<const bf16x8*>(&wbp[nrow*128 + (kb ^ nsw)]);
        accp[rt] = __builtin_amdgcn_mfma_f32_16x16x32_bf16(a, bb, accp[rt], 0,0,0);
      }
    }
  };

  // ---- phase A: xr = y@Wo^T + bo + x ----
  { int rr = tid>>3, q = tid&7, sw = (rr&7)<<3;        // y tile -> f1 (ys)
    const ushort_t* src = yg + (size_t)(m0+rr)*128 + q*16;
    *reinterpret_cast<us8*>(&f1[rr*128 + ((q*16)   ^ sw)]) = *reinterpret_cast<const us8*>(src);
    *reinterpret_cast<us8*>(&f1[rr*128 + ((q*16+8) ^ sw)]) = *reinterpret_cast<const us8*>(src+8);
  }
  stageW(Wo, 128, 0);
  __syncthreads();
  f32x4 accA[2][2];
  #pragma unroll
  for (int s_=0;s_<2;++s_){ accA[s_][0]=(f32x4){0,0,0,0}; accA[s_][1]=(f32x4){0,0,0,0}; }
  stageW(Wo + 64*128, 128, 1);
  gemmT(f1, 0, accA[0]);
  __syncthreads();
  gemmT(f1, 1, accA[1]);
  #pragma unroll
  for (int s_=0; s_<2; ++s_){
    int col = s_*64 + wid*16 + (lane&15);
    float bia = bo[col];
    #pragma unroll
    for (int rt=0; rt<2; ++rt)
      #pragma unroll
      for (int rr=0; rr<4; ++rr){
        int row = rt*16 + (lane>>4)*4 + rr;
        xr[row*132 + col] = accA[s_][rt][rr] + bia + x[(size_t)(m0+row)*128 + col];
      }
  }
  __syncthreads();

  // ---- LN2 -> h2 ----
  { int r = tid>>3, q = tid&7;
    float xv[16];
    #pragma unroll
    for (int i=0;i<16;i++) xv[i] = xr[r*132 + q*16 + i];
    float s = 0;
    #pragma unroll
    for (int i=0;i<16;i++) s += xv[i];
    s += __shfl_xor(s,1); s += __shfl_xor(s,2); s += __shfl_xor(s,4);
    float mean = s * (1.0f/128.0f);
    float vs = 0;
    #pragma unroll
    for (int i=0;i<16;i++){ float d = xv[i]-mean; vs += d*d; }
    vs += __shfl_xor(vs,1); vs += __shfl_xor(vs,2); vs += __shfl_xor(vs,4);
    float rstd = rsqrtf(vs*(1.0f/128.0f) + 1e-5f);
    int sw = (r&7)<<3;
    #pragma unroll
    for (int g=0; g<2; ++g){
      us8 o;
      #pragma unroll
      for (int j=0;j<8;j++){
        int c = q*16 + g*8 + j;
        o[j] = f2bf((xv[g*8+j]-mean)*rstd*g2[c] + b2g[c]);
      }
      *reinterpret_cast<us8*>(&h2[r*128 + ((q*16+g*8) ^ sw)]) = o;
    }
  }
  stageW(W1, 128, 0);      // W1 c=0 sub=0
  __syncthreads();

  // ---- phases B+C interleaved per 128-col chunk c ----
  f32x4 acc2[2][2];
  #pragma unroll
  for (int s_=0;s_<2;++s_){ acc2[s_][0]=(f32x4){0,0,0,0}; acc2[s_][1]=(f32x4){0,0,0,0}; }
  int buf = 0;
  for (int c=0; c<4; ++c){
    // seg1: stage W1 sub1 -> buf^1 ; f1 cols 0..63 from buf
    stageW(W1 + (size_t)(c*128+64)*128, 128, buf^1);
    { f32x4 ac[2] = {(f32x4){0,0,0,0},(f32x4){0,0,0,0}};
      gemmT(h2, buf, ac);
      int cl = wid*16 + (lane&15);
      float bia = b1v[c*128 + cl];
      #pragma unroll
      for (int rt=0; rt<2; ++rt)
        #pragma unroll
        for (int rr=0; rr<4; ++rr){
          int row = rt*16 + (lane>>4)*4 + rr;
          float v = ac[rt][rr] + bia;
          v = 0.5f*v*(1.0f + erff(v*0.70710678118654752f));
          f1[row*128 + (cl ^ ((row&7)<<3))] = f2bf(v);
        }
    }
    __syncthreads();
    // seg2: stage W2 nn0 -> buf ; f1 cols 64..127 from buf^1
    stageW(W2 + (size_t)c*128, 512, buf);
    { f32x4 ac[2] = {(f32x4){0,0,0,0},(f32x4){0,0,0,0}};
      gemmT(h2, buf^1, ac);
      int cl = 64 + wid*16 + (lane&15);
      float bia = b1v[c*128 + cl];
      #pragma unroll
      for (int rt=0; rt<2; ++rt)
        #pragma unroll
        for (int rr=0; rr<4; ++rr){
          int row = rt*16 + (lane>>4)*4 + rr;
          float v = ac[rt][rr] + bia;
          v = 0.5f*v*(1.0f + erff(v*0.70710678118654752f));
          f1[row*128 + (cl ^ ((row&7)<<3))] = f2bf(v);
        }
    }
    __syncthreads();
    // seg3: stage W2 nn1 -> buf^1 ; acc2[0] += f1 @ W2nn0 (buf)
    stageW(W2 + (size_t)64*512 + (size_t)c*128, 512, buf^1);
    gemmT(f1, buf, acc2[0]);
    __syncthreads();
    // seg4: stage W1 (c+1) sub0 -> buf ; acc2[1] += f1 @ W2nn1 (buf^1)
    if (c < 3) stageW(W1 + (size_t)((c+1)*128)*128, 128, buf);
    gemmT(f1, buf^1, acc2[1]);
    __syncthreads();
  }

  // ---- final: out = acc2 + b2 + xr ----
  #pragma unroll
  for (int s_=0; s_<2; ++s_){
    int col = s_*64 + wid*16 + (lane&15);
    float bia = b2v[col];
    #pragma unroll
    for (int rt=0; rt<2; ++rt)
      #pragma unroll
      for (int rr=0; rr<4; ++rr){
        int row = rt*16 + (lane>>4)*4 + rr;
        float v = acc2[s_][rt][rr] + bia + xr[row*132 + col];
        if constexpr (HEAD) xr[row*132 + col] = v;
        else                x[(size_t)(m0+row)*128 + col] = v;
      }
  }
  if constexpr (HEAD){
    __syncthreads();
    for (int r = wid; r < 32; r += 4){
      int s = m0 + r, b = s / LTK, p = s - b*LTK;
      if (p % 3 != 1) continue;
      int t = p / 3;
      float v1 = xr[r*132 + lane];
      float v2 = xr[r*132 + 64 + lane];
      float sum = v1 + v2;
      sum += __shfl_xor(sum,1); sum += __shfl_xor(sum,2); sum += __shfl_xor(sum,4);
      sum += __shfl_xor(sum,8); sum += __shfl_xor(sum,16); sum += __shfl_xor(sum,32);
      float mean = sum*(1.0f/128.0f);
      float d1 = v1-mean, d2 = v2-mean;
      float var = d1*d1 + d2*d2;
      var += __shfl_xor(var,1); var += __shfl_xor(var,2); var += __shfl_xor(var,4);
      var += __shfl_xor(var,8); var += __shfl_xor(var,16); var += __shfl_xor(var,32);
      float rstd = rsqrtf(var*(1.0f/128.0f) + 1e-5f);
      float h1 = d1*rstd*lnfg[lane]    + lnfb[lane];
      float h2v= d2*rstd*lnfg[lane+64] + lnfb[lane+64];
      #pragma unroll
      for (int o=0; o<NV; ++o){
        float sdot = h1*hw[o*128+lane] + h2v*hw[o*128+lane+64];
        sdot += __shfl_xor(sdot,1); sdot += __shfl_xor(sdot,2); sdot += __shfl_xor(sdot,4);
        sdot += __shfl_xor(sdot,8); sdot += __shfl_xor(sdot,16); sdot += __shfl_xor(sdot,32);
        if (lane == 0) out[(size_t)(b*NT+t)*NV + o] = sdot;
      }
    }
  }
}

// ===========================================================================
extern "C" void kernel_launch(void* const* d_in, const int* in_sizes, int n_in,
                              void* d_out, int out_size, void* d_ws, size_t ws_size,
                              hipStream_t stream)
{
  const float* states  = (const float*)d_in[0];
  const int*   actions = (const int*)  d_in[1];
  const float* rtgs    = (const float*)d_in[2];
  const int*   tsteps  = (const int*)  d_in[3];
  const float* conv_w  = (const float*)d_in[4];
  const float* ctok    = (const float*)d_in[5];
  const float* in_w    = (const float*)d_in[6];
  const float* in_b    = (const float*)d_in[7];
  const float* out_w   = (const float*)d_in[8];
  const float* out_b   = (const float*)d_in[9];
  const float* i1g     = (const float*)d_in[10];
  const float* i1b     = (const float*)d_in[11];
  const float* i2g     = (const float*)d_in[12];
  const float* i2b     = (const float*)d_in[13];
  const float* fw1     = (const float*)d_in[14];
  const float* fb1     = (const float*)d_in[15];
  const float* fw2     = (const float*)d_in[16];
  const float* fb2     = (const float*)d_in[17];
  const float* ret_w   = (const float*)d_in[18];
  const float* ret_b   = (const float*)d_in[19];
  const float* act_tab = (const float*)d_in[20];
  const float* pos_emb = (const float*)d_in[21];
  const float* gpos    = (const float*)d_in[22];
  const float* ln1g    = (const float*)d_in[23];
  const float* ln1b    = (const float*)d_in[24];
  const float* Wq      = (const float*)d_in[25];
  const float* bq      = (const float*)d_in[26];
  const float* Wk      = (const float*)d_in[27];
  const float* bk      = (const float*)d_in[28];
  const float* Wv      = (const float*)d_in[29];
  const float* bv      = (const float*)d_in[30];
  const float* Wo      = (const float*)d_in[31];
  const float* bo      = (const float*)d_in[32];
  const float* ln2g    = (const float*)d_in[33];
  const float* ln2b    = (const float*)d_in[34];
  const float* W1      = (const float*)d_in[35];
  const float* b1      = (const float*)d_in[36];
  const float* W2      = (const float*)d_in[37];
  const float* b2      = (const float*)d_in[38];
  const float* lnfg    = (const float*)d_in[39];
  const float* lnfb    = (const float*)d_in[40];
  const float* head_w  = (const float*)d_in[41];

  char* w = (char*)d_ws;
  size_t off = 0;
  auto alloc = [&](size_t bytes)->char* {
    char* p = w + off; off += (bytes + 255) & ~(size_t)255; return p;
  };
  float*    part  = (float*)   alloc((size_t)NZ*NBT*EE*4);
  float*    x     = (float*)   alloc((size_t)NS*EE*4);
  ushort_t* yb    = (ushort_t*)alloc((size_t)NS*EE*2);
  ushort_t* cwb   = (ushort_t*)alloc((size_t)EE*KP*2);
  ushort_t* Wqkvb = (ushort_t*)alloc((size_t)NLY*384*128*2);
  ushort_t* Wob   = (ushort_t*)alloc((size_t)NLY*128*128*2);
  ushort_t* W1b   = (ushort_t*)alloc((size_t)NLY*512*128*2);
  ushort_t* W2b   = (ushort_t*)alloc((size_t)NLY*128*512*2);
  float*    t_in  = (float*)   alloc(384*128*4);
  float*    t_out = (float*)   alloc(128*128*4);
  float*    t_f1  = (float*)   alloc(128*128*4);
  float*    t_f2  = (float*)   alloc(128*128*4);
  float*    bqkv  = (float*)   alloc(NLY*384*4);
  (void)in_sizes; (void)n_in; (void)out_size; (void)ws_size;

  wcvt<<<4872,256,0,stream>>>(conv_w,Wq,Wk,Wv,Wo,W1,W2,
                              in_w,out_w,fw1,fw2, bq,bk,bv,
                              cwb,Wqkvb,Wob,W1b,W2b,
                              t_in,t_out,t_f1,t_f2, bqkv);
  patch_gemm<<<dim3(30,1,NZ),256,0,stream>>>(states, cwb, part);
  inner_tit<<<NBT,128,0,stream>>>(part, ctok, t_in, in_b, t_out, out_b,
                                  i1g,i1b,i2g,i2b, t_f1,fb1, t_f2,fb2,
                                  rtgs, actions, tsteps, ret_w, ret_b, act_tab,
                                  pos_emb, gpos, x);
  for (int i=0;i<NLY;i++){
    attn_fused<<<512,256,0,stream>>>(
      x, Wqkvb+(size_t)i*49152, bqkv+(size_t)i*384, ln1g+i*128, ln1b+i*128, yb);
    if (i < NLY-1)
      ffn_fused<false><<<178,256,0,stream>>>(
        yb, Wob+(size_t)i*16384, bo+i*128, ln2g+i*128, ln2b+i*128,
        W1b+(size_t)i*65536, b1+i*512, W2b+(size_t)i*65536, b2+i*128, x,
        nullptr, nullptr, nullptr, nullptr);
    else
      ffn_fused<true><<<178,256,0,stream>>>(
        yb, Wob+(size_t)i*16384, bo+i*128, ln2g+i*128, ln2b+i*128,
        W1b+(size_t)i*65536, b1+i*512, W2b+(size_t)i*65536, b2+i*128, x,
        lnfg, lnfb, head_w, (float*)d_out);
  }
}

// Round 7
// 341.798 us; speedup vs baseline: 14.5022x; 1.2111x over previous
//
#include <hip/hip_runtime.h>

#define NB   64
#define NT   30
#define NBT  1920        // NB*NT
#define EE   128
#define KP   28224       // 4*84*84
#define LTK  89          // 3*NT-1
#define NS   5696        // NB*LTK
#define NLY  6
#define NV   18
#define NZ   21          // split-K slabs for patch gemm

typedef unsigned short ushort_t;
using bf16x8 = __attribute__((ext_vector_type(8))) short;
using us8    = __attribute__((ext_vector_type(8))) unsigned short;
using f32x4  = __attribute__((ext_vector_type(4))) float;
using f32x16 = __attribute__((ext_vector_type(16))) float;

__device__ inline ushort_t f2bf(float f){
  union { float f; unsigned u; } v; v.f = f;
  unsigned r = v.u + 0x7FFFu + ((v.u >> 16) & 1u);   // RNE
  return (ushort_t)(r >> 16);
}

// ------- weights fp32->bf16 (incl. inner weights) + qkv bias pack ----------
__global__ __launch_bounds__(256) void wcvt(
  const float* conv, const float* Wq, const float* Wk, const float* Wv,
  const float* Wo, const float* W1, const float* W2,
  const float* in_w, const float* out_w, const float* f1w, const float* f2w,
  const float* bq, const float* bk, const float* bv,
  ushort_t* dc, ushort_t* dqkv, ushort_t* dout, ushort_t* d1, ushort_t* d2,
  ushort_t* dinw, ushort_t* doutw, ushort_t* df1, ushort_t* df2, float* bqkv)
{
  if (blockIdx.x >= 4776){                  // bias-pack tail
    int idx = (blockIdx.x-4776)*256 + threadIdx.x;
    if (idx < NLY*128){ int l=idx>>7, j=idx&127;
      bqkv[l*384+j]=bq[idx]; bqkv[l*384+128+j]=bk[idx]; bqkv[l*384+256+j]=bv[idx]; }
    return;
  }
  long i = 4l*((long)blockIdx.x*256 + threadIdx.x);
  if (i >= 3612672l && i < 3907584l){      // Wq | Wk | Wv  ->  (L,384,128)
    long o = i - 3612672l;
    int  seg = (int)(o / 98304l);
    long off2 = o - (long)seg*98304l;
    long layer = off2 >> 14, rem = off2 & 16383l;
    const float* s = (seg==0) ? Wq : (seg==1) ? Wk : Wv;
    float4 f = *reinterpret_cast<const float4*>(s+off2);
    long dst = layer*49152l + (long)seg*16384l + rem;
    dqkv[dst]=f2bf(f.x); dqkv[dst+1]=f2bf(f.y); dqkv[dst+2]=f2bf(f.z); dqkv[dst+3]=f2bf(f.w);
    return;
  }
  const float* s; ushort_t* d; long off;
  if      (i < 3612672l){ s=conv;  d=dc;    off=i; }
  else if (i < 4005888l){ s=Wo;    d=dout;  off=i-3907584l; }
  else if (i < 4399104l){ s=W1;    d=d1;    off=i-4005888l; }
  else if (i < 4792320l){ s=W2;    d=d2;    off=i-4399104l; }
  else if (i < 4841472l){ s=in_w;  d=dinw;  off=i-4792320l; }
  else if (i < 4857856l){ s=out_w; d=doutw; off=i-4841472l; }
  else if (i < 4874240l){ s=f1w;   d=df1;   off=i-4857856l; }
  else                  { s=f2w;   d=df2;   off=i-4874240l; }
  float4 f = *reinterpret_cast<const float4*>(s+off);
  d[off]=f2bf(f.x); d[off+1]=f2bf(f.y); d[off+2]=f2bf(f.z); d[off+3]=f2bf(f.w);
}

// -------- patch embed: BM=64, split-K slabs, register-prefetch pipeline ----
__global__ __launch_bounds__(256) void patch_gemm(
  const float* __restrict__ A, const ushort_t* __restrict__ Wb, float* __restrict__ C)
{
  __shared__ __align__(16) ushort_t As[64*64];
  __shared__ __align__(16) ushort_t Ws[128*64];
  const int tid = threadIdx.x, lane = tid & 63, wid = tid >> 6;
  const int m0 = blockIdx.x * 64;
  const int kbase = blockIdx.z * 1344;
  float* Cz = C + (size_t)blockIdx.z * NBT * EE;
  const int ra = tid>>2, ca = (tid&3)*16, swa = (ra&7)<<3;
  const int rw = tid>>1, cw = (tid&1)*32, sww = (rw&7)<<3;
  const float*    Ab = A  + (size_t)(m0+ra)*KP + kbase + ca;
  const ushort_t* Wp = Wb + (size_t)rw*KP  + kbase + cw;
  f32x4 acc[8];
  #pragma unroll
  for (int j=0;j<8;j++) acc[j] = (f32x4){0.f,0.f,0.f,0.f};
  float4 fa[4]; us8 wr[4];
  #pragma unroll
  for (int q=0;q<4;q++) fa[q] = *reinterpret_cast<const float4*>(Ab + 4*q);
  #pragma unroll
  for (int q=0;q<4;q++) wr[q] = *reinterpret_cast<const us8*>(Wp + 8*q);

  for (int kt = 0; kt < 21; ++kt){
    { us8 o0, o1;
      o0[0]=f2bf(fa[0].x); o0[1]=f2bf(fa[0].y); o0[2]=f2bf(fa[0].z); o0[3]=f2bf(fa[0].w);
      o0[4]=f2bf(fa[1].x); o0[5]=f2bf(fa[1].y); o0[6]=f2bf(fa[1].z); o0[7]=f2bf(fa[1].w);
      o1[0]=f2bf(fa[2].x); o1[1]=f2bf(fa[2].y); o1[2]=f2bf(fa[2].z); o1[3]=f2bf(fa[2].w);
      o1[4]=f2bf(fa[3].x); o1[5]=f2bf(fa[3].y); o1[6]=f2bf(fa[3].z); o1[7]=f2bf(fa[3].w);
      *reinterpret_cast<us8*>(&As[ra*64 + ( ca    ^ swa)]) = o0;
      *reinterpret_cast<us8*>(&As[ra*64 + ((ca+8) ^ swa)]) = o1;
      #pragma unroll
      for (int q=0;q<4;q++)
        *reinterpret_cast<us8*>(&Ws[rw*64 + ((cw+8*q) ^ sww)]) = wr[q];
    }
    if (kt < 20){
      #pragma unroll
      for (int q=0;q<4;q++) fa[q] = *reinterpret_cast<const float4*>(Ab + (kt+1)*64 + 4*q);
      #pragma unroll
      for (int q=0;q<4;q++) wr[q] = *reinterpret_cast<const us8*>(Wp + (kt+1)*64 + 8*q);
    }
    __syncthreads();
    #pragma unroll
    for (int ks=0; ks<2; ++ks){
      int arow = wid*16 + (lane&15);
      int kb = ks*32 + (lane>>4)*8;
      bf16x8 a = *reinterpret_cast<const bf16x8*>(&As[arow*64 + (kb ^ ((arow&7)<<3))]);
      #pragma unroll
      for (int nt=0; nt<8; ++nt){
        int nn = nt*16 + (lane&15);
        bf16x8 b = *reinterpret_cast<const bf16x8*>(&Ws[nn*64 + (kb ^ ((nn&7)<<3))]);
        acc[nt] = __builtin_amdgcn_mfma_f32_16x16x32_bf16(a, b, acc[nt], 0,0,0);
      }
    }
    __syncthreads();
  }
  #pragma unroll
  for (int nt=0; nt<8; ++nt)
    #pragma unroll
    for (int rr=0;rr<4;rr++){
      int row = m0 + wid*16 + (lane>>4)*4 + rr;
      int col = nt*16 + (lane&15);
      Cz[row*EE + col] = acc[nt][rr];
    }
}

// ======= inner TIT v2: 8 bt per block, MFMA, staged bf16 weights ===========
__global__ __launch_bounds__(256, 1) void inner_tit(
  const float* __restrict__ part, const float* __restrict__ ctok,
  const ushort_t* __restrict__ inw, const float* __restrict__ in_b,
  const ushort_t* __restrict__ outw, const float* __restrict__ out_b,
  const float* __restrict__ g1, const float* __restrict__ b1_,
  const float* __restrict__ g2, const float* __restrict__ b2_,
  const ushort_t* __restrict__ f1wb, const float* __restrict__ fb1,
  const ushort_t* __restrict__ f2wb, const float* __restrict__ fb2,
  const float* __restrict__ rtgs, const int* __restrict__ actions,
  const int* __restrict__ tsteps, const float* __restrict__ ret_w,
  const float* __restrict__ ret_b, const float* __restrict__ act_tab,
  const float* __restrict__ pos_emb, const float* __restrict__ gpos,
  const float* __restrict__ ln1g0, const float* __restrict__ ln1b0,
  float* __restrict__ x, ushort_t* __restrict__ xln)
{
  __shared__ __align__(16) ushort_t wbuf[384*128];   // 96KB staged weights
  __shared__ float xs[16*128];                        // residual stream
  __shared__ __align__(16) ushort_t hb[16*128];      // bf16 A-operand buffer
  __shared__ __align__(16) ushort_t hf[16*128];      // FFN1 out
  __shared__ float qkv[16*384];
  __shared__ float ssm[32];
  const int tid = threadIdx.x, lane = tid & 63, wid = tid >> 6;
  const int bt0 = blockIdx.x * 8;

  auto stageWB = [&](const ushort_t* src, int R, int rowoff){
    for (int c = tid; c < R*16; c += 256){
      int rr = c >> 4, cc = (c & 15) * 8;
      *reinterpret_cast<us8*>(&wbuf[(rowoff+rr)*128 + (cc ^ ((rr&7)<<3))]) =
        *reinterpret_cast<const us8*>(src + (size_t)rr*128 + cc);
    }
  };
  auto lnrow = [&](const float* gam, const float* bet, ushort_t* dst){
    int r = tid >> 4, e0 = (tid & 15) * 8;
    float v[8];
    #pragma unroll
    for (int j=0;j<8;j++) v[j] = xs[r*128 + e0 + j];
    float s = 0;
    #pragma unroll
    for (int j=0;j<8;j++) s += v[j];
    s += __shfl_xor(s,1); s += __shfl_xor(s,2); s += __shfl_xor(s,4); s += __shfl_xor(s,8);
    float mean = s * (1.0f/128.0f);
    float vs = 0;
    #pragma unroll
    for (int j=0;j<8;j++){ float d = v[j]-mean; vs += d*d; }
    vs += __shfl_xor(vs,1); vs += __shfl_xor(vs,2); vs += __shfl_xor(vs,4); vs += __shfl_xor(vs,8);
    float rstd = rsqrtf(vs*(1.0f/128.0f) + 1e-5f);
    us8 o;
    #pragma unroll
    for (int j=0;j<8;j++) o[j] = f2bf((v[j]-mean)*rstd*gam[e0+j] + bet[e0+j]);
    *reinterpret_cast<us8*>(&dst[r*128 + (e0 ^ ((r&7)<<3))]) = o;
  };

  // P0: load X (even rows = class token, odd = patch sum over NZ slabs)
  { int r = tid >> 4, e0 = (tid & 15) * 8;
    float v[8];
    if ((r & 1) == 0){
      #pragma unroll
      for (int j=0;j<8;j++) v[j] = ctok[e0+j];
    } else {
      #pragma unroll
      for (int j=0;j<8;j++) v[j] = 0.f;
      int bt = bt0 + (r>>1);
      for (int z=0; z<NZ; ++z){
        const float* p = part + (size_t)z*NBT*EE + (size_t)bt*128 + e0;
        float4 f0 = *reinterpret_cast<const float4*>(p);
        float4 f1 = *reinterpret_cast<const float4*>(p+4);
        v[0]+=f0.x; v[1]+=f0.y; v[2]+=f0.z; v[3]+=f0.w;
        v[4]+=f1.x; v[5]+=f1.y; v[6]+=f1.z; v[7]+=f1.w;
      }
    }
    #pragma unroll
    for (int j=0;j<8;j++) xs[r*128 + e0 + j] = v[j];
  }
  stageWB(inw, 384, 0);
  __syncthreads();

  // P1: LN1 -> hb
  lnrow(g1, b1_, hb);
  __syncthreads();

  // P2: QKV gemm (16 x 384, K=128)
  { int al = lane & 15, kq = (lane>>4)*8;
    #pragma unroll
    for (int j=0;j<6;++j){
      int nt = wid*6 + j;
      f32x4 acc = (f32x4){0.f,0.f,0.f,0.f};
      int nrow = nt*16 + al, nsw = (nrow&7)<<3;
      #pragma unroll
      for (int ks=0; ks<4; ++ks){
        int kb = ks*32 + kq;
        bf16x8 a = *reinterpret_cast<const bf16x8*>(&hb[al*128 + (kb ^ ((al&7)<<3))]);
        bf16x8 b = *reinterpret_cast<const bf16x8*>(&wbuf[nrow*128 + (kb ^ nsw)]);
        acc = __builtin_amdgcn_mfma_f32_16x16x32_bf16(a, b, acc, 0,0,0);
      }
      float bia = in_b[nt*16 + al];
      #pragma unroll
      for (int rr=0; rr<4; ++rr){
        int row = (lane>>4)*4 + rr;
        qkv[row*384 + nt*16 + al] = acc[rr] + bia;
      }
    }
  }
  __syncthreads();

  // P3: 2x2 attention dots (+ stage out/f1/f2 weights in parallel)
  { int d = tid >> 3, j = tid & 7;
    int i = d >> 2, p = d & 3;
    const float* qp = &qkv[(2*i + (p>>1))*384 + j*16];
    const float* kp = &qkv[(2*i + (p&1))*384 + 128 + j*16];
    float s = 0;
    #pragma unroll
    for (int e=0;e<16;e++) s += qp[e]*kp[e];
    s += __shfl_xor(s,1); s += __shfl_xor(s,2); s += __shfl_xor(s,4);
    if (j == 0) ssm[d] = s;
  }
  stageWB(outw, 128, 0);
  stageWB(f1wb, 128, 128);
  stageWB(f2wb, 128, 256);
  __syncthreads();

  // P4: softmax(2) + PV -> hb
  { int r = tid >> 4, e0 = (tid & 15)*8;
    int i = r >> 1, t = r & 1;
    const float sc = 0.08838834764831845f;
    float s0 = ssm[i*4 + t*2]*sc, s1 = ssm[i*4 + t*2 + 1]*sc;
    float m = fmaxf(s0,s1), p0 = __expf(s0-m), p1 = __expf(s1-m);
    float iv = 1.0f/(p0+p1); p0 *= iv; p1 *= iv;
    const float* v0 = &qkv[(2*i)*384 + 256 + e0];
    const float* v1 = &qkv[(2*i+1)*384 + 256 + e0];
    us8 o;
    #pragma unroll
    for (int j=0;j<8;j++) o[j] = f2bf(p0*v0[j] + p1*v1[j]);
    *reinterpret_cast<us8*>(&hb[r*128 + (e0 ^ ((r&7)<<3))]) = o;
  }
  __syncthreads();

  // P5: out-proj += xs
  { int al = lane & 15, kq = (lane>>4)*8;
    #pragma unroll
    for (int j=0;j<2;++j){
      int nt = wid*2 + j;
      f32x4 acc = (f32x4){0.f,0.f,0.f,0.f};
      int nrow = nt*16 + al, nsw = (nrow&7)<<3;
      #pragma unroll
      for (int ks=0; ks<4; ++ks){
        int kb = ks*32 + kq;
        bf16x8 a = *reinterpret_cast<const bf16x8*>(&hb[al*128 + (kb ^ ((al&7)<<3))]);
        bf16x8 b = *reinterpret_cast<const bf16x8*>(&wbuf[nrow*128 + (kb ^ nsw)]);
        acc = __builtin_amdgcn_mfma_f32_16x16x32_bf16(a, b, acc, 0,0,0);
      }
      float bia = out_b[nt*16 + al];
      #pragma unroll
      for (int rr=0; rr<4; ++rr){
        int row = (lane>>4)*4 + rr;
        xs[row*128 + nt*16 + al] += acc[rr] + bia;
      }
    }
  }
  __syncthreads();

  // P6: LN2 -> hb
  lnrow(g2, b2_, hb);
  __syncthreads();

  // P7: FFN1 + relu -> hf   (weights at wbuf rows 128..255)
  { int al = lane & 15, kq = (lane>>4)*8;
    #pragma unroll
    for (int j=0;j<2;++j){
      int nt = wid*2 + j;
      f32x4 acc = (f32x4){0.f,0.f,0.f,0.f};
      int nrow = nt*16 + al, nsw = (nrow&7)<<3;
      #pragma unroll
      for (int ks=0; ks<4; ++ks){
        int kb = ks*32 + kq;
        bf16x8 a = *reinterpret_cast<const bf16x8*>(&hb[al*128 + (kb ^ ((al&7)<<3))]);
        bf16x8 b = *reinterpret_cast<const bf16x8*>(&wbuf[(128+nrow)*128 + (kb ^ nsw)]);
        acc = __builtin_amdgcn_mfma_f32_16x16x32_bf16(a, b, acc, 0,0,0);
      }
      float bia = fb1[nt*16 + al];
      #pragma unroll
      for (int rr=0; rr<4; ++rr){
        int row = (lane>>4)*4 + rr;
        hf[row*128 + ((nt*16+al) ^ ((row&7)<<3))] = f2bf(fmaxf(acc[rr] + bia, 0.f));
      }
    }
  }
  __syncthreads();

  // P8: FFN2 += xs   (weights at wbuf rows 256..383)
  { int al = lane & 15, kq = (lane>>4)*8;
    #pragma unroll
    for (int j=0;j<2;++j){
      int nt = wid*2 + j;
      f32x4 acc = (f32x4){0.f,0.f,0.f,0.f};
      int nrow = nt*16 + al, nsw = (nrow&7)<<3;
      #pragma unroll
      for (int ks=0; ks<4; ++ks){
        int kb = ks*32 + kq;
        bf16x8 a = *reinterpret_cast<const bf16x8*>(&hf[al*128 + (kb ^ ((al&7)<<3))]);
        bf16x8 b = *reinterpret_cast<const bf16x8*>(&wbuf[(256+nrow)*128 + (kb ^ nsw)]);
        acc = __builtin_amdgcn_mfma_f32_16x16x32_bf16(a, b, acc, 0,0,0);
      }
      float bia = fb2[nt*16 + al];
      #pragma unroll
      for (int rr=0; rr<4; ++rr){
        int row = (lane>>4)*4 + rr;
        xs[row*128 + nt*16 + al] += acc[rr] + bia;
      }
    }
  }
  __syncthreads();

  // P9: token interleave + positional -> x (f32) and xln = LN1_L0 (bf16)
  { int q = tid >> 3, j = tid & 7;
    if (q < 24){
      int i = q / 3, kind = q - 3*i;         // 0 rtg, 1 state, 2 act
      int btg = bt0 + i, b = btg / NT, t = btg - b*NT;
      bool valid = !(kind == 2 && t == 0);
      if (valid){
        int prow = (kind==0) ? 3*t : (kind==1) ? 3*t+1 : 3*t-1;
        size_t xrow = ((size_t)b*LTK + prow)*128;
        int ts = tsteps[b];
        int e0 = j*16;
        float v[16];
        if (kind == 1){
          #pragma unroll
          for (int e=0;e<16;e++) v[e] = xs[(2*i)*128 + e0 + e];
        } else if (kind == 0){
          float rv = rtgs[b*NT+t];
          #pragma unroll
          for (int e=0;e<16;e++) v[e] = tanhf(rv*ret_w[e0+e] + ret_b[e0+e]);
        } else {
          int a = actions[b*NT+t];
          #pragma unroll
          for (int e=0;e<16;e++) v[e] = tanhf(act_tab[a*128 + e0 + e]);
        }
        #pragma unroll
        for (int e=0;e<16;e++)
          v[e] += gpos[(size_t)ts*128 + e0 + e] + pos_emb[prow*128 + e0 + e];
        #pragma unroll
        for (int e=0;e<16;e++) x[xrow + e0 + e] = v[e];
        float s = 0;
        #pragma unroll
        for (int e=0;e<16;e++) s += v[e];
        s += __shfl_xor(s,1); s += __shfl_xor(s,2); s += __shfl_xor(s,4);
        float mean = s * (1.0f/128.0f);
        float vs = 0;
        #pragma unroll
        for (int e=0;e<16;e++){ float d = v[e]-mean; vs += d*d; }
        vs += __shfl_xor(vs,1); vs += __shfl_xor(vs,2); vs += __shfl_xor(vs,4);
        float rstd = rsqrtf(vs*(1.0f/128.0f) + 1e-5f);
        #pragma unroll
        for (int e=0;e<16;e++)
          xln[xrow + e0 + e] = f2bf((v[e]-mean)*rstd*ln1g0[e0+e] + ln1b0[e0+e]);
      }
    }
  }
}

// ======== fused attention: one block per (b,h); reads pre-LN'd xln =========
__global__ __launch_bounds__(256, 2) void attn_fused(
  const ushort_t* __restrict__ xln, const ushort_t* __restrict__ Wqkv,
  const float* __restrict__ bqkv, ushort_t* __restrict__ y)
{
  __shared__ __align__(16) char sm[69504];
  ushort_t* ab  = (ushort_t*)sm;              // [96][128] bf16 swz (24576)
  ushort_t* wb  = (ushort_t*)(sm + 24576);    // [48][128] bf16 swz (12288)
  float*    S   = (float*)sm;                 // [96][97] f32 union ab/wb
  ushort_t* qa  = (ushort_t*)(sm + 37248);    // [96][22] bf16
  ushort_t* ka  = (ushort_t*)(sm + 41472);    // [96][22]
  ushort_t* vta = (ushort_t*)(sm + 45696);    // [16][108] V^T
  ushort_t* pb  = (ushort_t*)(sm + 49152);    // [96][104]
  float*    inv = (float*)(sm + 69120);       // [96]

  const int b = blockIdx.x >> 3, h = blockIdx.x & 7;
  const int tid = threadIdx.x, lane = tid & 63, wid = tid >> 6;

  // ---- phase 0: stage xln -> ab ; stage wb (48 head rows) ----
  for (int idx = tid; idx < 1536; idx += 256){
    int row = idx >> 4, c0 = (idx & 15) * 8;
    us8 v;
    if (row < LTK) v = *reinterpret_cast<const us8*>(xln + ((size_t)(b*LTK+row))*128 + c0);
    else           v = (us8){0,0,0,0,0,0,0,0};
    *reinterpret_cast<us8*>(&ab[row*128 + (c0 ^ ((row&7)<<3))]) = v;
  }
  for (int idx = tid; idx < 384; idx += 256){   // wb: 48 rows x 128
    int rr = idx >> 3, c = (idx & 7) * 16;
    int seg = rr >> 4, n = rr & 15;
    const ushort_t* src = Wqkv + (size_t)(seg*128 + h*16 + n)*128 + c;
    int sw = (rr&7)<<3;
    *reinterpret_cast<us8*>(&wb[rr*128 + ( c    ^ sw)]) = *reinterpret_cast<const us8*>(src);
    *reinterpret_cast<us8*>(&wb[rr*128 + ((c+8) ^ sw)]) = *reinterpret_cast<const us8*>(src+8);
  }
  __syncthreads();

  // ---- phase 1: QKV gemm (96x48, K=128) -> qa, ka, vta ----
  for (int idx = wid; idx < 18; idx += 4){
    int rt = idx / 3, nt = idx - 3*(idx/3);
    f32x4 acc = (f32x4){0.f,0.f,0.f,0.f};
    int arow = rt*16 + (lane&15), asw = (arow&7)<<3;
    int nrow = nt*16 + (lane&15), nsw = (nrow&7)<<3;
    #pragma unroll
    for (int ks=0; ks<4; ++ks){
      int kb = ks*32 + (lane>>4)*8;
      bf16x8 a = *reinterpret_cast<const bf16x8*>(&ab[arow*128 + (kb ^ asw)]);
      bf16x8 bf = *reinterpret_cast<const bf16x8*>(&wb[nrow*128 + (kb ^ nsw)]);
      acc = __builtin_amdgcn_mfma_f32_16x16x32_bf16(a, bf, acc, 0,0,0);
    }
    int d = lane & 15;
    float bia = bqkv[nt*128 + h*16 + d];
    #pragma unroll
    for (int rr=0; rr<4; ++rr){
      int rg = rt*16 + (lane>>4)*4 + rr;
      ushort_t hv = f2bf(acc[rr] + bia);
      if      (nt == 0) qa[rg*22 + d] = hv;
      else if (nt == 1) ka[rg*22 + d] = hv;
      else              vta[d*108 + rg] = hv;
    }
  }
  __syncthreads();

  // ---- phase 2: S = Q K^T * 0.25 (lower-tri 32x32 tiles) ----
  {
    static const int TR[6] = {0,1,1,2,2,2};
    static const int TC[6] = {0,0,1,0,1,2};
    for (int idx = wid; idx < 6; idx += 4){
      int R = TR[idx], C = TC[idx];
      int arow = R*32 + (lane&31), brow = C*32 + (lane&31);
      int ke = (lane>>5)*8;
      bf16x8 a  = *reinterpret_cast<const bf16x8*>(&qa[arow*22 + ke]);
      bf16x8 bf = *reinterpret_cast<const bf16x8*>(&ka[brow*22 + ke]);
      f32x16 sc = {};
      sc = __builtin_amdgcn_mfma_f32_32x32x16_bf16(a, bf, sc, 0,0,0);
      #pragma unroll
      for (int r=0; r<16; ++r){
        int rin = (r&3) + 8*(r>>2) + 4*(lane>>5);
        S[(R*32+rin)*97 + C*32 + (lane&31)] = sc[r]*0.25f;
      }
    }
  }
  __syncthreads();

  // ---- phase 3: softmax rows -> pb (bf16), inv ----
  if (tid < 192){
    int t = tid >> 1, half = tid & 1;
    int u0 = half*48;
    float mx = -1e30f;
    if (t < LTK){
      for (int u=u0; u<u0+48; ++u) if (u<=t) mx = fmaxf(mx, S[t*97+u]);
    }
    mx = fmaxf(mx, __shfl_xor(mx,1));
    float smv = 0;
    if (t < LTK){
      for (int u=u0; u<u0+48; ++u){
        float p = 0;
        if (u<=t){ p = __expf(S[t*97+u]-mx); smv += p; }
        pb[t*104+u] = f2bf(p);
      }
    } else {
      for (int u=u0; u<u0+48; ++u) pb[t*104+u] = 0;
    }
    smv += __shfl_xor(smv,1);
    if (half==0) inv[t] = (t<LTK) ? 1.0f/smv : 0.0f;
  }
  __syncthreads();

  // ---- phase 4: O = P V -> y ----
  for (int rt = wid; rt < 6; rt += 4){
    int arow = rt*16 + (lane&15);
    f32x4 acc = (f32x4){0.f,0.f,0.f,0.f};
    #pragma unroll
    for (int ks=0; ks<3; ++ks){
      int kb = ks*32 + (lane>>4)*8;
      bf16x8 a  = *reinterpret_cast<const bf16x8*>(&pb[arow*104 + kb]);
      bf16x8 bf = *reinterpret_cast<const bf16x8*>(&vta[(lane&15)*108 + kb]);
      acc = __builtin_amdgcn_mfma_f32_16x16x32_bf16(a, bf, acc, 0,0,0);
    }
    #pragma unroll
    for (int rr=0; rr<4; ++rr){
      int rg = rt*16 + (lane>>4)*4 + rr;
      if (rg < LTK)
        y[(size_t)(b*LTK+rg)*128 + h*16 + (lane&15)] = f2bf(acc[rr]*inv[rg]);
    }
  }
}

// ======== fused FFN: Wo+res -> LN2 -> FFN1(gelu) -> FFN2+res -> xln/head ===
template<bool HEAD>
__global__ __launch_bounds__(256, 2) void ffn_fused(
  const ushort_t* __restrict__ yg, const ushort_t* __restrict__ Wo,
  const float* __restrict__ bo, const float* __restrict__ g2,
  const float* __restrict__ b2g, const ushort_t* __restrict__ W1,
  const float* __restrict__ b1v, const ushort_t* __restrict__ W2,
  const float* __restrict__ b2v, float* __restrict__ x,
  const float* __restrict__ lnng, const float* __restrict__ lnnb,
  ushort_t* __restrict__ xlnout,
  const float* __restrict__ lnfg, const float* __restrict__ lnfb,
  const float* __restrict__ hw, float* __restrict__ out)
{
  __shared__ __align__(16) char sm[66304];
  ushort_t* wbs = (ushort_t*)sm;             // [2][64][128] swz  32768
  float*    xr  = (float*)(sm + 32768);      // [32][132] f32    16896
  ushort_t* h2  = (ushort_t*)(sm + 49664);   // [32][128] swz     8192
  ushort_t* f1  = (ushort_t*)(sm + 57856);   // [32][128] swz     8192 (=ys in A)
  const int tid = threadIdx.x, lane = tid & 63, wid = tid >> 6;
  const int m0 = blockIdx.x * 32;

  auto stageW = [&](const ushort_t* src_base, size_t stride, int buf){
    int rr = tid >> 2, q = tid & 3, sw = (rr&7)<<3;
    const ushort_t* s = src_base + (size_t)rr*stride + q*32;
    ushort_t* d = wbs + buf*8192 + rr*128;
    #pragma unroll
    for (int g=0; g<4; ++g)
      *reinterpret_cast<us8*>(&d[(q*32+g*8) ^ sw]) =
        *reinterpret_cast<const us8*>(s + g*8);
  };
  auto gemmT = [&](const ushort_t* abuf, int buf, f32x4* accp){
    int nrow = wid*16 + (lane&15), nsw = (nrow&7)<<3;
    const ushort_t* wbp = wbs + buf*8192;
    #pragma unroll
    for (int rt=0; rt<2; ++rt){
      int arow = rt*16 + (lane&15), asw = (arow&7)<<3;
      #pragma unroll
      for (int ks=0; ks<4; ++ks){
        int kb = ks*32 + (lane>>4)*8;
        bf16x8 a = *reinterpret_cast<const bf16x8*>(&abuf[arow*128 + (kb ^ asw)]);
        bf16x8 bb = *reinterpret_cast<const bf16x8*>(&wbp[nrow*128 + (kb ^ nsw)]);
        accp[rt] = __builtin_amdgcn_mfma_f32_16x16x32_bf16(a, bb, accp[rt], 0,0,0);
      }
    }
  };

  // ---- phase A: xr = y@Wo^T + bo + x ----
  { int rr = tid>>3, q = tid&7, sw = (rr&7)<<3;
    const ushort_t* src = yg + (size_t)(m0+rr)*128 + q*16;
    *reinterpret_cast<us8*>(&f1[rr*128 + ((q*16)   ^ sw)]) = *reinterpret_cast<const us8*>(src);
    *reinterpret_cast<us8*>(&f1[rr*128 + ((q*16+8) ^ sw)]) = *reinterpret_cast<const us8*>(src+8);
  }
  stageW(Wo, 128, 0);
  __syncthreads();
  f32x4 accA[2][2];
  #pragma unroll
  for (int s_=0;s_<2;++s_){ accA[s_][0]=(f32x4){0,0,0,0}; accA[s_][1]=(f32x4){0,0,0,0}; }
  stageW(Wo + 64*128, 128, 1);
  gemmT(f1, 0, accA[0]);
  __syncthreads();
  gemmT(f1, 1, accA[1]);
  #pragma unroll
  for (int s_=0; s_<2; ++s_){
    int col = s_*64 + wid*16 + (lane&15);
    float bia = bo[col];
    #pragma unroll
    for (int rt=0; rt<2; ++rt)
      #pragma unroll
      for (int rr=0; rr<4; ++rr){
        int row = rt*16 + (lane>>4)*4 + rr;
        xr[row*132 + col] = accA[s_][rt][rr] + bia + x[(size_t)(m0+row)*128 + col];
      }
  }
  __syncthreads();

  // ---- LN2 -> h2 ----
  { int r = tid>>3, q = tid&7;
    float xv[16];
    #pragma unroll
    for (int i=0;i<16;i++) xv[i] = xr[r*132 + q*16 + i];
    float s = 0;
    #pragma unroll
    for (int i=0;i<16;i++) s += xv[i];
    s += __shfl_xor(s,1); s += __shfl_xor(s,2); s += __shfl_xor(s,4);
    float mean = s * (1.0f/128.0f);
    float vs = 0;
    #pragma unroll
    for (int i=0;i<16;i++){ float d = xv[i]-mean; vs += d*d; }
    vs += __shfl_xor(vs,1); vs += __shfl_xor(vs,2); vs += __shfl_xor(vs,4);
    float rstd = rsqrtf(vs*(1.0f/128.0f) + 1e-5f);
    int sw = (r&7)<<3;
    #pragma unroll
    for (int g=0; g<2; ++g){
      us8 o;
      #pragma unroll
      for (int j=0;j<8;j++){
        int c = q*16 + g*8 + j;
        o[j] = f2bf((xv[g*8+j]-mean)*rstd*g2[c] + b2g[c]);
      }
      *reinterpret_cast<us8*>(&h2[r*128 + ((q*16+g*8) ^ sw)]) = o;
    }
  }
  stageW(W1, 128, 0);
  __syncthreads();

  // ---- phases B+C interleaved per 128-col chunk c ----
  f32x4 acc2[2][2];
  #pragma unroll
  for (int s_=0;s_<2;++s_){ acc2[s_][0]=(f32x4){0,0,0,0}; acc2[s_][1]=(f32x4){0,0,0,0}; }
  int buf = 0;
  for (int c=0; c<4; ++c){
    stageW(W1 + (size_t)(c*128+64)*128, 128, buf^1);
    { f32x4 ac[2] = {(f32x4){0,0,0,0},(f32x4){0,0,0,0}};
      gemmT(h2, buf, ac);
      int cl = wid*16 + (lane&15);
      float bia = b1v[c*128 + cl];
      #pragma unroll
      for (int rt=0; rt<2; ++rt)
        #pragma unroll
        for (int rr=0; rr<4; ++rr){
          int row = rt*16 + (lane>>4)*4 + rr;
          float v = ac[rt][rr] + bia;
          v = 0.5f*v*(1.0f + erff(v*0.70710678118654752f));
          f1[row*128 + (cl ^ ((row&7)<<3))] = f2bf(v);
        }
    }
    __syncthreads();
    stageW(W2 + (size_t)c*128, 512, buf);
    { f32x4 ac[2] = {(f32x4){0,0,0,0},(f32x4){0,0,0,0}};
      gemmT(h2, buf^1, ac);
      int cl = 64 + wid*16 + (lane&15);
      float bia = b1v[c*128 + cl];
      #pragma unroll
      for (int rt=0; rt<2; ++rt)
        #pragma unroll
        for (int rr=0; rr<4; ++rr){
          int row = rt*16 + (lane>>4)*4 + rr;
          float v = ac[rt][rr] + bia;
          v = 0.5f*v*(1.0f + erff(v*0.70710678118654752f));
          f1[row*128 + (cl ^ ((row&7)<<3))] = f2bf(v);
        }
    }
    __syncthreads();
    stageW(W2 + (size_t)64*512 + (size_t)c*128, 512, buf^1);
    gemmT(f1, buf, acc2[0]);
    __syncthreads();
    if (c < 3) stageW(W1 + (size_t)((c+1)*128)*128, 128, buf);
    gemmT(f1, buf^1, acc2[1]);
    __syncthreads();
  }

  // ---- final: v = acc2 + b2 + xr -> x, xr ----
  #pragma unroll
  for (int s_=0; s_<2; ++s_){
    int col = s_*64 + wid*16 + (lane&15);
    float bia = b2v[col];
    #pragma unroll
    for (int rt=0; rt<2; ++rt)
      #pragma unroll
      for (int rr=0; rr<4; ++rr){
        int row = rt*16 + (lane>>4)*4 + rr;
        float v = acc2[s_][rt][rr] + bia + xr[row*132 + col];
        xr[row*132 + col] = v;
        if constexpr (!HEAD) x[(size_t)(m0+row)*128 + col] = v;
      }
  }
  __syncthreads();
  if constexpr (!HEAD){
    // write next layer's LN1(x) as bf16 xln
    int r = tid>>3, q = tid&7;
    float xv[16];
    #pragma unroll
    for (int i=0;i<16;i++) xv[i] = xr[r*132 + q*16 + i];
    float s = 0;
    #pragma unroll
    for (int i=0;i<16;i++) s += xv[i];
    s += __shfl_xor(s,1); s += __shfl_xor(s,2); s += __shfl_xor(s,4);
    float mean = s * (1.0f/128.0f);
    float vs = 0;
    #pragma unroll
    for (int i=0;i<16;i++){ float d = xv[i]-mean; vs += d*d; }
    vs += __shfl_xor(vs,1); vs += __shfl_xor(vs,2); vs += __shfl_xor(vs,4);
    float rstd = rsqrtf(vs*(1.0f/128.0f) + 1e-5f);
    #pragma unroll
    for (int g=0; g<2; ++g){
      us8 o;
      #pragma unroll
      for (int j=0;j<8;j++){
        int c = q*16 + g*8 + j;
        o[j] = f2bf((xv[g*8+j]-mean)*rstd*lnng[c] + lnnb[c]);
      }
      *reinterpret_cast<us8*>(xlnout + (size_t)(m0+r)*128 + q*16 + g*8) = o;
    }
  } else {
    for (int r = wid; r < 32; r += 4){
      int s = m0 + r, b = s / LTK, p = s - b*LTK;
      if (p % 3 != 1) continue;
      int t = p / 3;
      float v1 = xr[r*132 + lane];
      float v2 = xr[r*132 + 64 + lane];
      float sum = v1 + v2;
      sum += __shfl_xor(sum,1); sum += __shfl_xor(sum,2); sum += __shfl_xor(sum,4);
      sum += __shfl_xor(sum,8); sum += __shfl_xor(sum,16); sum += __shfl_xor(sum,32);
      float mean = sum*(1.0f/128.0f);
      float d1 = v1-mean, d2 = v2-mean;
      float var = d1*d1 + d2*d2;
      var += __shfl_xor(var,1); var += __shfl_xor(var,2); var += __shfl_xor(var,4);
      var += __shfl_xor(var,8); var += __shfl_xor(var,16); var += __shfl_xor(var,32);
      float rstd = rsqrtf(var*(1.0f/128.0f) + 1e-5f);
      float h1 = d1*rstd*lnfg[lane]    + lnfb[lane];
      float h2v= d2*rstd*lnfg[lane+64] + lnfb[lane+64];
      #pragma unroll
      for (int o=0; o<NV; ++o){
        float sdot = h1*hw[o*128+lane] + h2v*hw[o*128+lane+64];
        sdot += __shfl_xor(sdot,1); sdot += __shfl_xor(sdot,2); sdot += __shfl_xor(sdot,4);
        sdot += __shfl_xor(sdot,8); sdot += __shfl_xor(sdot,16); sdot += __shfl_xor(sdot,32);
        if (lane == 0) out[(size_t)(b*NT+t)*NV + o] = sdot;
      }
    }
  }
}

// ===========================================================================
extern "C" void kernel_launch(void* const* d_in, const int* in_sizes, int n_in,
                              void* d_out, int out_size, void* d_ws, size_t ws_size,
                              hipStream_t stream)
{
  const float* states  = (const float*)d_in[0];
  const int*   actions = (const int*)  d_in[1];
  const float* rtgs    = (const float*)d_in[2];
  const int*   tsteps  = (const int*)  d_in[3];
  const float* conv_w  = (const float*)d_in[4];
  const float* ctok    = (const float*)d_in[5];
  const float* in_w    = (const float*)d_in[6];
  const float* in_b    = (const float*)d_in[7];
  const float* out_w   = (const float*)d_in[8];
  const float* out_b   = (const float*)d_in[9];
  const float* i1g     = (const float*)d_in[10];
  const float* i1b     = (const float*)d_in[11];
  const float* i2g     = (const float*)d_in[12];
  const float* i2b     = (const float*)d_in[13];
  const float* fw1     = (const float*)d_in[14];
  const float* fb1     = (const float*)d_in[15];
  const float* fw2     = (const float*)d_in[16];
  const float* fb2     = (const float*)d_in[17];
  const float* ret_w   = (const float*)d_in[18];
  const float* ret_b   = (const float*)d_in[19];
  const float* act_tab = (const float*)d_in[20];
  const float* pos_emb = (const float*)d_in[21];
  const float* gpos    = (const float*)d_in[22];
  const float* ln1g    = (const float*)d_in[23];
  const float* ln1b    = (const float*)d_in[24];
  const float* Wq      = (const float*)d_in[25];
  const float* bq      = (const float*)d_in[26];
  const float* Wk      = (const float*)d_in[27];
  const float* bk      = (const float*)d_in[28];
  const float* Wv      = (const float*)d_in[29];
  const float* bv      = (const float*)d_in[30];
  const float* Wo      = (const float*)d_in[31];
  const float* bo      = (const float*)d_in[32];
  const float* ln2g    = (const float*)d_in[33];
  const float* ln2b    = (const float*)d_in[34];
  const float* W1      = (const float*)d_in[35];
  const float* b1      = (const float*)d_in[36];
  const float* W2      = (const float*)d_in[37];
  const float* b2      = (const float*)d_in[38];
  const float* lnfg    = (const float*)d_in[39];
  const float* lnfb    = (const float*)d_in[40];
  const float* head_w  = (const float*)d_in[41];

  char* w = (char*)d_ws;
  size_t off = 0;
  auto alloc = [&](size_t bytes)->char* {
    char* p = w + off; off += (bytes + 255) & ~(size_t)255; return p;
  };
  float*    part  = (float*)   alloc((size_t)NZ*NBT*EE*4);
  float*    x     = (float*)   alloc((size_t)NS*EE*4);
  ushort_t* xln   = (ushort_t*)alloc((size_t)NS*EE*2);
  ushort_t* yb    = (ushort_t*)alloc((size_t)NS*EE*2);
  ushort_t* cwb   = (ushort_t*)alloc((size_t)EE*KP*2);
  ushort_t* Wqkvb = (ushort_t*)alloc((size_t)NLY*384*128*2);
  ushort_t* Wob   = (ushort_t*)alloc((size_t)NLY*128*128*2);
  ushort_t* W1b   = (ushort_t*)alloc((size_t)NLY*512*128*2);
  ushort_t* W2b   = (ushort_t*)alloc((size_t)NLY*128*512*2);
  ushort_t* inwb  = (ushort_t*)alloc((size_t)384*128*2);
  ushort_t* outwb = (ushort_t*)alloc((size_t)128*128*2);
  ushort_t* f1wb  = (ushort_t*)alloc((size_t)128*128*2);
  ushort_t* f2wb  = (ushort_t*)alloc((size_t)128*128*2);
  float*    bqkv  = (float*)   alloc(NLY*384*4);
  (void)in_sizes; (void)n_in; (void)out_size; (void)ws_size;

  wcvt<<<4779,256,0,stream>>>(conv_w,Wq,Wk,Wv,Wo,W1,W2,
                              in_w,out_w,fw1,fw2, bq,bk,bv,
                              cwb,Wqkvb,Wob,W1b,W2b,
                              inwb,outwb,f1wb,f2wb, bqkv);
  patch_gemm<<<dim3(30,1,NZ),256,0,stream>>>(states, cwb, part);
  inner_tit<<<240,256,0,stream>>>(part, ctok, inwb, in_b, outwb, out_b,
                                  i1g,i1b,i2g,i2b, f1wb,fb1, f2wb,fb2,
                                  rtgs, actions, tsteps, ret_w, ret_b, act_tab,
                                  pos_emb, gpos, ln1g, ln1b, x, xln);
  for (int i=0;i<NLY;i++){
    attn_fused<<<512,256,0,stream>>>(
      xln, Wqkvb+(size_t)i*49152, bqkv+(size_t)i*384, yb);
    if (i < NLY-1)
      ffn_fused<false><<<178,256,0,stream>>>(
        yb, Wob+(size_t)i*16384, bo+i*128, ln2g+i*128, ln2b+i*128,
        W1b+(size_t)i*65536, b1+i*512, W2b+(size_t)i*65536, b2+i*128, x,
        ln1g+(i+1)*128, ln1b+(i+1)*128, xln,
        nullptr, nullptr, nullptr, nullptr);
    else
      ffn_fused<true><<<178,256,0,stream>>>(
        yb, Wob+(size_t)i*16384, bo+i*128, ln2g+i*128, ln2b+i*128,
        W1b+(size_t)i*65536, b1+i*512, W2b+(size_t)i*65536, b2+i*128, x,
        nullptr, nullptr, nullptr,
        lnfg, lnfb, head_w, (float*)d_out);
  }
}